// Round 13
// baseline (671.312 us; speedup 1.0000x reference)
//
#include <hip/hip_runtime.h>

// EMA codebook update (VQ-VAE), MI355X. fp16-MFMA distance filter + exact
// fp32 rescore for near-ties. N=32768, K=8192, D=256.
// R13: gemm K-loop -> counted-vmcnt pipeline (T3/T4): Bs 4-ring (32 KB),
//      s_waitcnt vmcnt(2) + raw s_barrier (loads stay in flight across
//      barriers, no drain), setprio around MFMA cluster (T5), running
//      B source pointer. Rest identical to R12.

#define DECAY 0.99f
#define OMD 0.01f
#define EPS 1e-5f
#define DELTA 0.3f

constexpr int N = 32768, K = 8192, D = 256;
constexpr int KSPLIT = 2;               // gemm grid: 256 row-tiles x 2 code-splits
constexpr int BMt = 128, BNt = 128;     // gemm tile
constexpr int GT = 512;                 // gemm threads (8 waves: 2M x 4N)

// resolve config
constexpr int RBM = 64;                 // flagged rows per group
constexpr int RBN = 128;                // codes per K-split
constexpr int RKS = 64;                 // K splits
constexpr int RSL = 16;                 // group slots

typedef _Float16 f16x8 __attribute__((ext_vector_type(8)));
typedef float f32x4 __attribute__((ext_vector_type(4)));

// d_out layout (floats, reference return order)
constexpr long Q_OFF   = 0;
constexpr long IDX_OFF = (long)N * D;
constexpr long CB_OFF  = IDX_OFF + N;
constexpr long EMB_OFF = CB_OFF + (long)K * D;
constexpr long CS_OFF  = EMB_OFF + (long)K * D;

// ws layout (bytes)
constexpr long WS_TOPS = 0;                          // ulonglong2[N*KSPLIT]
constexpr long WS_RES  = WS_TOPS + (long)N * 2 * 16; // u64[N] resolved
constexpr long WS_IDX  = WS_RES + (long)N * 8;       // int[N]
constexpr long WS_C2   = WS_IDX + (long)N * 4;       // float[K]
constexpr long WS_FLAG = WS_C2 + (long)K * 4;        // int[N] flagged rows
constexpr long WS_CNT  = WS_FLAG + (long)N * 4;      // [0] u32 count, [1] f32 nacc
constexpr long WS_CNTS = WS_CNT + 8;                 // int[K] histogram
constexpr long WS_CUR  = WS_CNTS + (long)K * 4;      // int[K] scan/cursor
constexpr long WS_SORT = WS_CUR + (long)K * 4;       // int[N] rows sorted by code

#define GLOAD_LDS16(g, l) __builtin_amdgcn_global_load_lds(                    \
    (const __attribute__((address_space(1))) void*)(g),                        \
    (__attribute__((address_space(3))) void*)(l), 16, 0, 0)

__device__ inline unsigned transScore(float s) {
    unsigned u = __float_as_uint(s);
    return u ^ ((unsigned)((int)u >> 31) | 0x80000000u);   // order-preserving
}
__device__ inline float untransScore(unsigned u) {
    return (u & 0x80000000u) ? __uint_as_float(u ^ 0x80000000u)
                             : __uint_as_float(~u);
}

// prep: c2 + fp32->fp16 codebook + all workspace init. grid K x 64.
__global__ void prep_kernel(const float* __restrict__ cb, _Float16* __restrict__ cb16,
                            float* __restrict__ c2, char* __restrict__ ws) {
    int k = blockIdx.x, lane = threadIdx.x;
    float4 v = ((const float4*)(cb + (long)k * D))[lane];
    float s = v.x * v.x + v.y * v.y + v.z * v.z + v.w * v.w;
    for (int off = 32; off; off >>= 1) s += __shfl_xor(s, off);
    if (lane == 0) c2[k] = s;
    union { _Float16 h[4]; unsigned long long u; } t;
    t.h[0] = (_Float16)v.x; t.h[1] = (_Float16)v.y;
    t.h[2] = (_Float16)v.z; t.h[3] = (_Float16)v.w;
    *(unsigned long long*)(cb16 + (long)k * D + lane * 4) = t.u;
    if (k < N / 64) ((unsigned long long*)(ws + WS_RES))[k * 64 + lane] = ~0ull;
    if (lane == 0) ((int*)(ws + WS_CNTS))[k] = 0;
    if (k == 0 && lane == 0) ((unsigned*)(ws + WS_CNT))[0] = 0u;
}

// ---------------- fp16 MFMA distance GEMM with top-2 tracking ----------------
__global__ __launch_bounds__(GT, 2) void gemm_kernel(
        const float* __restrict__ z, const _Float16* __restrict__ cb16,
        const float* __restrict__ c2, ulonglong2* __restrict__ tops) {
    __shared__ _Float16 As[BMt * 256];          // 64 KB, swizzled
    __shared__ _Float16 Bs[4][BNt * 32];        // 4-ring x 8 KB, swizzled
    // total 96 KB -> 1 block/CU; counted-vmcnt removes the barrier drain.

    const int tid = threadIdx.x;
    const int lane = tid & 63;
    const int wave = tid >> 6;                  // 8 waves: 2(M) x 4(N)
    const int wm = wave >> 2, wn = wave & 3;
    const long rowBase = (long)blockIdx.x * BMt;
    const int kbase = blockIdx.y * (K / KSPLIT);

    // ---- stage A (z rows) once: fp32 -> fp16, swizzled (validated layout) ----
    for (int i = 0; i < 8; ++i) {
        int id = tid + i * GT;                  // 4096 chunks of 8 floats
        int r = id >> 5, dseg = (id & 31) * 8;
        const float4* src = (const float4*)(z + (rowBase + r) * D + dseg);
        float4 v0 = src[0], v1 = src[1];
        union { _Float16 h[8]; ulonglong2 u; } t;
        t.h[0] = (_Float16)v0.x; t.h[1] = (_Float16)v0.y;
        t.h[2] = (_Float16)v0.z; t.h[3] = (_Float16)v0.w;
        t.h[4] = (_Float16)v1.x; t.h[5] = (_Float16)v1.y;
        t.h[6] = (_Float16)v1.z; t.h[7] = (_Float16)v1.w;
        int byte = (r * 256 + dseg) * 2;
        byte ^= (r & 7) << 4;
        *(ulonglong2*)((char*)As + byte) = t.u;
    }

    // ---- per-thread B-staging slot: inverse of the LDS read swizzle ----
    int bc, bt;
    {
        int h = tid >> 3, rr = tid & 7;
        bc = 2 * h; bt = rr ^ (bc & 7);
        if (bt & 4) { bc++; bt = (rr ^ (bc & 7)) & 3; }
    }
    char* ldsBbase = (char*)&Bs[0][0] + tid * 16;    // +ring*8192

    const int NCH = (K / KSPLIT / BNt) * 8;          // 256 chunks
    // running B source pointer: chunk (kb,dcI) = base + kb*BNt*256 + dcI*32
    const _Float16* srcPtr = cb16 + ((long)(kbase + bc) << 8) + bt * 8;
    // prologue: 3-deep prefetch (chunks 0,1,2; all dcI<7 so stride +32)
    GLOAD_LDS16(srcPtr, ldsBbase);             srcPtr += 32;
    GLOAD_LDS16(srcPtr, ldsBbase + 8192);      srcPtr += 32;
    GLOAD_LDS16(srcPtr, ldsBbase + 16384);     srcPtr += 32;

    // per-thread A/B frag byte offsets. A: xor applied AFTER adding dc.
    int aBase[4], aSwz[4], bOff[2];
#pragma unroll
    for (int fr = 0; fr < 4; ++fr) {
        int r = wm * 64 + fr * 16 + (lane & 15);
        aBase[fr] = r * 512 + (lane >> 4) * 16;
        aSwz[fr] = (r & 7) << 4;
    }
#pragma unroll
    for (int fc = 0; fc < 2; ++fc) {
        int c = wn * 32 + fc * 16 + (lane & 15);
        int byte = c * 64 + (lane >> 4) * 16;
        bOff[fc] = byte ^ ((c & 7) << 4);
    }

    f32x4 acc[4][2];
    float bV[16], bT2[16];
    int bI[16];
#pragma unroll
    for (int s = 0; s < 16; ++s) { bV[s] = 3.4e38f; bT2[s] = 3.4e38f; bI[s] = 0; }
    float c2v[2];

    asm volatile("s_waitcnt lgkmcnt(0)" ::: "memory");   // own A ds_writes done

    for (int j = 0; j < NCH; ++j) {
        // T4: counted wait — loads j+1, j+2 stay in flight across the barrier
        asm volatile("s_waitcnt vmcnt(2)" ::: "memory");
        __builtin_amdgcn_s_barrier();
        // issue chunk j+3 into ring slot (j+3)&3 == (j-1)&3 (readers passed bar)
        if (j + 3 < NCH) {
            GLOAD_LDS16(srcPtr, ldsBbase + (((j + 3) & 3) << 13));
            srcPtr += (((j + 3) & 7) == 7) ? (BNt * 256 - 7 * 32) : 32;
        }
        const int kb = j >> 3, dcI = j & 7, dc = dcI * 32;
        if (dcI == 0) {
#pragma unroll
            for (int a = 0; a < 4; ++a)
#pragma unroll
                for (int b = 0; b < 2; ++b) acc[a][b] = (f32x4)0.f;
#pragma unroll
            for (int fc = 0; fc < 2; ++fc)
                c2v[fc] = c2[kbase + kb * BNt + wn * 32 + fc * 16 + (lane & 15)];
        }
        f16x8 aF[4], bF[2];
#pragma unroll
        for (int fr = 0; fr < 4; ++fr)
            aF[fr] = *(const f16x8*)((const char*)As +
                        ((aBase[fr] + dc * 2) ^ aSwz[fr]));
        const char* bp = (const char*)&Bs[0][0] + ((j & 3) << 13);
#pragma unroll
        for (int fc = 0; fc < 2; ++fc)
            bF[fc] = *(const f16x8*)(bp + bOff[fc]);
        __builtin_amdgcn_s_setprio(1);
#pragma unroll
        for (int fr = 0; fr < 4; ++fr)
#pragma unroll
            for (int fc = 0; fc < 2; ++fc)
                acc[fr][fc] = __builtin_amdgcn_mfma_f32_16x16x32_f16(
                    aF[fr], bF[fc], acc[fr][fc], 0, 0, 0);
        __builtin_amdgcn_s_setprio(0);
        if (dcI == 7) {
            // score + float top-2 (ties covered by DELTA rescore)
#pragma unroll
            for (int fc = 0; fc < 2; ++fc) {
                int gcol = kbase + kb * BNt + wn * 32 + fc * 16 + (lane & 15);
#pragma unroll
                for (int fr = 0; fr < 4; ++fr)
#pragma unroll
                    for (int r = 0; r < 4; ++r) {
                        float s = fmaf(-2.f, acc[fr][fc][r], c2v[fc]);
                        int slot = fr * 4 + r;
                        float t1o = bV[slot];
                        bT2[slot] = fminf(bT2[slot], fmaxf(s, t1o));
                        bool lt = s < t1o;
                        bV[slot] = lt ? s : t1o;
                        bI[slot] = lt ? gcol : bI[slot];
                    }
            }
        }
    }
    __syncthreads();                 // full drain before reusing Bs space

    // intra-wave top2 merge over the 16 lanes sharing each row (float domain)
#pragma unroll
    for (int m = 1; m < 16; m <<= 1) {
#pragma unroll
        for (int s = 0; s < 16; ++s) {
            float ov = __shfl_xor(bV[s], m);
            int   oi = __shfl_xor(bI[s], m);
            float o2 = __shfl_xor(bT2[s], m);
            float nt2 = fminf(fminf(bT2[s], o2), fmaxf(bV[s], ov));
            bool take = ov < bV[s];
            bV[s] = take ? ov : bV[s];
            bI[s] = take ? oi : bI[s];
            bT2[s] = nt2;
        }
    }
    // cross-wave (4 wn waves) top2 merge via LDS atomicMin-displacement,
    // arrays unioned into Bs (K-loop done, drained).
    unsigned long long* L1 = (unsigned long long*)&Bs[0][0];   // 1 KB
    unsigned* L2s = (unsigned*)(L1 + BMt);                     // 512 B
    if (tid < BMt) { L1[tid] = ~0ull; L2s[tid] = 0xFFFFFFFFu; }
    __syncthreads();
    if ((lane & 15) == 0) {
#pragma unroll
        for (int s = 0; s < 16; ++s) {
            int row = wm * 64 + (s >> 2) * 16 + (lane >> 4) * 4 + (s & 3);
            unsigned long long t1 =
                ((unsigned long long)transScore(bV[s]) << 32) | (unsigned)bI[s];
            unsigned long long old1 = atomicMin(&L1[row], t1);
            unsigned long long cand = t1 < old1 ? old1 : t1;
            atomicMin(&L2s[row], (unsigned)(cand >> 32));
            atomicMin(&L2s[row], transScore(bT2[s]));
        }
    }
    __syncthreads();
    if (tid < BMt) {
        ulonglong2 v; v.x = L1[tid]; v.y = (unsigned long long)L2s[tid];
        tops[(rowBase + tid) * KSPLIT + blockIdx.y] = v;
    }
}

// merge + histogram of confidently-resolved rows
__global__ void merge_kernel(const ulonglong2* __restrict__ tops,
                             float* __restrict__ out, int* __restrict__ idxArr,
                             unsigned* __restrict__ flagCount,
                             int* __restrict__ flagRows, int* __restrict__ counts) {
    int row = blockIdx.x * 256 + threadIdx.x;
    ulonglong2 a = tops[row * 2], b = tops[row * 2 + 1];
    unsigned long long t1 = a.x < b.x ? a.x : b.x;
    unsigned a1 = (unsigned)(a.x >> 32), b1 = (unsigned)(b.x >> 32);
    unsigned mx = a1 > b1 ? a1 : b1;
    unsigned t2 = (unsigned)a.y < (unsigned)b.y ? (unsigned)a.y : (unsigned)b.y;
    t2 = t2 < mx ? t2 : mx;
    float s1 = untransScore((unsigned)(t1 >> 32));
    float s2 = untransScore(t2);
    int idx = (int)(t1 & 0xFFFFFFFFull);
    idxArr[row] = idx;
    out[IDX_OFF + row] = (float)idx;
    if (s2 - s1 <= DELTA) {
        unsigned p = atomicAdd(flagCount, 1u);
        flagRows[p] = row;
    } else {
        atomicAdd(&counts[idx], 1);
    }
}

// exact fp32 rescore of flagged rows. Grid (RSL slots, RKS splits of RBN codes).
// One 64x128 tile per group-iteration; 4x4 thread tile; R2-style staging.
__global__ __launch_bounds__(512) void resolve_kernel(
        const float* __restrict__ z, const float* __restrict__ cb,
        const float* __restrict__ c2, const unsigned* __restrict__ flagCount,
        const int* __restrict__ flagRows, unsigned long long* __restrict__ resolved) {
    __shared__ float zT[32][RBM + 4];       // [d][row], 8.7 KB
    __shared__ float cT[32][RBN + 4];       // [d][code], 16.9 KB
    __shared__ float c2s[RBN];
    __shared__ int rid[RBM];

    const int cnt = (int)*flagCount;
    const int tid = threadIdx.x;
    const int tx = tid & 31, ty = tid >> 5;     // ty 0..15
    const int rbase = ty * 4, cbase = tx * 4;
    const int k0 = blockIdx.y * RBN;

    if (tid < RBN) c2s[tid] = c2[k0 + tid];

    for (int g = blockIdx.x; g * RBM < cnt; g += RSL) {
        __syncthreads();                    // previous group fully done
        if (tid < RBM) {
            int fi = g * RBM + tid;
            rid[tid] = flagRows[fi < cnt ? fi : cnt - 1];   // pad = dup (harmless)
        }

        float acc[4][4];
#pragma unroll
        for (int r = 0; r < 4; ++r)
#pragma unroll
            for (int c = 0; c < 4; ++c) acc[r][c] = 0.f;

        for (int dc = 0; dc < D; dc += 32) {
            __syncthreads();                // rid visible; prev reads done
            // stage z: 64 rows x 8 float4 = 512 slots (1 per thread)
            {
                int row = tid >> 3, dq = tid & 7;
                float4 v = *(const float4*)(z + (long)rid[row] * D + dc + dq * 4);
                zT[dq * 4 + 0][row] = v.x; zT[dq * 4 + 1][row] = v.y;
                zT[dq * 4 + 2][row] = v.z; zT[dq * 4 + 3][row] = v.w;
            }
            // stage cT: 128 codes x 8 float4 = 1024 slots (2 per thread)
#pragma unroll
            for (int i = 0; i < 2; ++i) {
                int id = tid + i * 512;
                int c = id >> 3, dq = id & 7;
                float4 w = *(const float4*)(cb + (long)(k0 + c) * D + dc + dq * 4);
                cT[dq * 4 + 0][c] = w.x; cT[dq * 4 + 1][c] = w.y;
                cT[dq * 4 + 2][c] = w.z; cT[dq * 4 + 3][c] = w.w;
            }
            __syncthreads();
#pragma unroll
            for (int d = 0; d < 32; ++d) {
                float a[4], b[4];
                *(float4*)&a[0] = *(const float4*)&zT[d][rbase];   // bcast x2
                *(float4*)&b[0] = *(const float4*)&cT[d][cbase];
#pragma unroll
                for (int r = 0; r < 4; ++r)
#pragma unroll
                    for (int c = 0; c < 4; ++c)
                        acc[r][c] = fmaf(a[r], b[c], acc[r][c]);
            }
        }
        // score + per-row best over this block's 128 codes
        float bestV[4]; int bestI[4];
#pragma unroll
        for (int r = 0; r < 4; ++r) { bestV[r] = 3.4e38f; bestI[r] = 0; }
#pragma unroll
        for (int c = 0; c < 4; ++c) {
            float cc = c2s[cbase + c];
            int col = k0 + cbase + c;
#pragma unroll
            for (int r = 0; r < 4; ++r) {
                float score = fmaf(-2.f, acc[r][c], cc);
                if (score < bestV[r]) { bestV[r] = score; bestI[r] = col; }
            }
        }
        // reduce over the 32 tx lanes (codes); first-index ties
#pragma unroll
        for (int off = 16; off; off >>= 1) {
#pragma unroll
            for (int r = 0; r < 4; ++r) {
                float ov = __shfl_xor(bestV[r], off);
                int   oi = __shfl_xor(bestI[r], off);
                if (ov < bestV[r] || (ov == bestV[r] && oi < bestI[r])) {
                    bestV[r] = ov; bestI[r] = oi;
                }
            }
        }
        if (tx == 0) {
#pragma unroll
            for (int r = 0; r < 4; ++r) {
                unsigned long long u =
                    ((unsigned long long)transScore(bestV[r]) << 32)
                    | (unsigned)bestI[r];
                atomicMin(&resolved[rid[rbase + r]], u);
            }
        }
    }
}

// writeback + histogram of flagged rows
__global__ void writeback_kernel(const unsigned* __restrict__ flagCount,
                                 const int* __restrict__ flagRows,
                                 const unsigned long long* __restrict__ resolved,
                                 int* __restrict__ idxArr, float* __restrict__ out,
                                 int* __restrict__ counts) {
    int i = blockIdx.x * 256 + threadIdx.x;
    if (i < (int)*flagCount) {
        int row = flagRows[i];
        int idx = (int)(resolved[row] & 0xFFFFFFFFull);
        idxArr[row] = idx;
        out[IDX_OFF + row] = (float)idx;
        atomicAdd(&counts[idx], 1);
    }
}

// single block: exclusive scan of counts -> cursor, CS output, n scalar
__global__ __launch_bounds__(1024) void scan_kernel(
        const int* __restrict__ counts, const float* __restrict__ cs,
        int* __restrict__ cursor, float* __restrict__ out,
        float* __restrict__ nacc) {
    __shared__ int wtot[16];
    __shared__ float csred[16];
    int tid = threadIdx.x;
    int lane = tid & 63, w = tid >> 6;
    int base = tid * 8;                 // 8192 / 1024
    int4 c0 = ((const int4*)(counts + base))[0];
    int4 c1 = ((const int4*)(counts + base))[1];
    float4 f0 = ((const float4*)(cs + base))[0];
    float4 f1 = ((const float4*)(cs + base))[1];
    int local[8] = {c0.x, c0.y, c0.z, c0.w, c1.x, c1.y, c1.z, c1.w};
    float csv[8] = {f0.x, f0.y, f0.z, f0.w, f1.x, f1.y, f1.z, f1.w};
    int sum = 0; float csum = 0.f;
#pragma unroll
    for (int i = 0; i < 8; ++i) { sum += local[i]; csum += csv[i]; }
    // wave-inclusive scan of per-thread sums
    int inc = sum;
#pragma unroll
    for (int off = 1; off < 64; off <<= 1) {
        int v = __shfl_up(inc, off);
        if (lane >= off) inc += v;
    }
    // cs partial reduce per wave
    for (int off = 32; off; off >>= 1) csum += __shfl_xor(csum, off);
    if (lane == 63) wtot[w] = inc;
    if (lane == 0) csred[w] = csum;
    __syncthreads();
    // wave 0 scans the 16 wave totals (exclusive)
    if (w == 0 && lane < 16) {
        int v = wtot[lane];
        int s2 = v;
#pragma unroll
        for (int off = 1; off < 16; off <<= 1) {
            int t = __shfl_up(s2, off);
            if (lane >= off) s2 += t;
        }
        wtot[lane] = s2 - v;            // exclusive wave offset
    }
    __syncthreads();
    int run = wtot[w] + (inc - sum);    // exclusive prefix of this thread chunk
#pragma unroll
    for (int i = 0; i < 8; ++i) {
        cursor[base + i] = run;
        out[CS_OFF + base + i] = csv[i] * DECAY + OMD * (float)local[i];
        run += local[i];
    }
    if (tid == 0) {
        float t = 0.f;
#pragma unroll
        for (int i = 0; i < 16; ++i) t += csred[i];
        *nacc = t * DECAY + OMD * (float)N;   // sum(counts) == N exactly
    }
}

// scatter (counting-sort placement) fused with quantized-gather copy
__global__ __launch_bounds__(512) void scatter_quantize_kernel(
        const float* __restrict__ cb, const int* __restrict__ idxArr,
        int* __restrict__ cursor, int* __restrict__ sorted,
        float* __restrict__ out) {
    int tid = threadIdx.x;
    int r = tid >> 2, seg = tid & 3;
    int gRow = blockIdx.x * 128 + r;
    int code = idxArr[gRow];
    if (seg == 0) {
        int pos = atomicAdd(&cursor[code], 1);
        sorted[pos] = gRow;
    }
    const float4* cbv = (const float4*)(cb + (long)code * D + seg * 64);
    float4* qv = (float4*)(out + Q_OFF + (long)gRow * D + seg * 64);
#pragma unroll 4
    for (int i = 0; i < 16; ++i) qv[i] = cbv[i];
}

// one wave per code: gather-sum its rows, write new_embedding_avg AND
// new_codebook (finalize folded in).
__global__ __launch_bounds__(256) void gather_sum_kernel(
        const float* __restrict__ z, const float* __restrict__ emb,
        const int* __restrict__ sorted, const int* __restrict__ cursor,
        const int* __restrict__ counts, const float* __restrict__ nacc,
        float* __restrict__ out) {
    int k = blockIdx.x * 4 + (threadIdx.x >> 6);
    int lane = threadIdx.x & 63;
    int cnt = counts[k];
    int start = cursor[k] - cnt;        // cursor was advanced by scatter
    float4 s = {0.f, 0.f, 0.f, 0.f};
    for (int i = 0; i < cnt; ++i) {
        int row = sorted[start + i];
        float4 v = *(const float4*)(z + (long)row * D + lane * 4);
        s.x += v.x; s.y += v.y; s.z += v.z; s.w += v.w;
    }
    float4 e = *(const float4*)(emb + (long)k * D + lane * 4);
    float4 o;
    o.x = e.x * DECAY + OMD * s.x;
    o.y = e.y * DECAY + OMD * s.y;
    o.z = e.z * DECAY + OMD * s.z;
    o.w = e.w * DECAY + OMD * s.w;
    *(float4*)(out + EMB_OFF + (long)k * D + lane * 4) = o;
    float n = *nacc;
    float ncs = out[CS_OFF + k];
    float smoothed = (ncs + EPS) / (n + (float)K * EPS) * n;
    float4 q;
    q.x = o.x / smoothed; q.y = o.y / smoothed;
    q.z = o.z / smoothed; q.w = o.w / smoothed;
    *(float4*)(out + CB_OFF + (long)k * D + lane * 4) = q;
}

extern "C" void kernel_launch(void* const* d_in, const int* in_sizes, int n_in,
                              void* d_out, int out_size, void* d_ws, size_t ws_size,
                              hipStream_t stream) {
    const float* z   = (const float*)d_in[0];
    const float* cb  = (const float*)d_in[1];
    const float* emb = (const float*)d_in[2];
    const float* cs  = (const float*)d_in[3];
    float* out = (float*)d_out;
    char* ws = (char*)d_ws;

    ulonglong2* tops = (ulonglong2*)(ws + WS_TOPS);
    unsigned long long* resolved = (unsigned long long*)(ws + WS_RES);
    int* idxArr = (int*)(ws + WS_IDX);
    float* c2 = (float*)(ws + WS_C2);
    int* flagRows = (int*)(ws + WS_FLAG);
    unsigned* flagCount = (unsigned*)(ws + WS_CNT);
    float* nacc = (float*)(ws + WS_CNT) + 1;
    int* counts = (int*)(ws + WS_CNTS);
    int* cursor = (int*)(ws + WS_CUR);
    int* sorted = (int*)(ws + WS_SORT);
    _Float16* cb16 = (_Float16*)(out + Q_OFF);   // scratch in quantized region

    prep_kernel<<<K, 64, 0, stream>>>(cb, cb16, c2, ws);
    dim3 ggrid(N / BMt, KSPLIT);
    gemm_kernel<<<ggrid, GT, 0, stream>>>(z, cb16, c2, tops);
    merge_kernel<<<N / 256, 256, 0, stream>>>(tops, out, idxArr, flagCount,
                                              flagRows, counts);
    dim3 rgrid(RSL, RKS);
    resolve_kernel<<<rgrid, 512, 0, stream>>>(z, cb, c2, flagCount, flagRows, resolved);
    writeback_kernel<<<N / 256, 256, 0, stream>>>(flagCount, flagRows, resolved,
                                                  idxArr, out, counts);
    scan_kernel<<<1, 1024, 0, stream>>>(counts, cs, cursor, out, nacc);
    scatter_quantize_kernel<<<N / 128, 512, 0, stream>>>(cb, idxArr, cursor,
                                                         sorted, out);
    gather_sum_kernel<<<K / 4, 256, 0, stream>>>(z, emb, sorted, cursor, counts,
                                                 nacc, out);
}

// Round 14
// 554.883 us; speedup vs baseline: 1.2098x; 1.2098x over previous
//
#include <hip/hip_runtime.h>

// EMA codebook update (VQ-VAE), MI355X. fp16-MFMA distance filter + exact
// fp32 rescore for near-ties. N=32768, K=8192, D=256.
// R14: revert gemm to R12 (2-blocks/CU, compiler-drain loop — proven 205us;
//      R13's counted-vmcnt ring regressed: 1 block/CU lost cross-block
//      overlap, +570cyc exposed latency/chunk). Tail identical to R12.

#define DECAY 0.99f
#define OMD 0.01f
#define EPS 1e-5f
#define DELTA 0.3f

constexpr int N = 32768, K = 8192, D = 256;
constexpr int KSPLIT = 2;               // gemm grid: 256 row-tiles x 2 code-splits
constexpr int BMt = 128, BNt = 128;     // gemm tile
constexpr int GT = 512;                 // gemm threads (8 waves: 2M x 4N)

// resolve config
constexpr int RBM = 64;                 // flagged rows per group
constexpr int RBN = 128;                // codes per K-split
constexpr int RKS = 64;                 // K splits
constexpr int RSL = 16;                 // group slots

typedef _Float16 f16x8 __attribute__((ext_vector_type(8)));
typedef float f32x4 __attribute__((ext_vector_type(4)));

// d_out layout (floats, reference return order)
constexpr long Q_OFF   = 0;
constexpr long IDX_OFF = (long)N * D;
constexpr long CB_OFF  = IDX_OFF + N;
constexpr long EMB_OFF = CB_OFF + (long)K * D;
constexpr long CS_OFF  = EMB_OFF + (long)K * D;

// ws layout (bytes)
constexpr long WS_TOPS = 0;                          // ulonglong2[N*KSPLIT]
constexpr long WS_RES  = WS_TOPS + (long)N * 2 * 16; // u64[N] resolved
constexpr long WS_IDX  = WS_RES + (long)N * 8;       // int[N]
constexpr long WS_C2   = WS_IDX + (long)N * 4;       // float[K]
constexpr long WS_FLAG = WS_C2 + (long)K * 4;        // int[N] flagged rows
constexpr long WS_CNT  = WS_FLAG + (long)N * 4;      // [0] u32 count, [1] f32 nacc
constexpr long WS_CNTS = WS_CNT + 8;                 // int[K] histogram
constexpr long WS_CUR  = WS_CNTS + (long)K * 4;      // int[K] scan/cursor
constexpr long WS_SORT = WS_CUR + (long)K * 4;       // int[N] rows sorted by code

#define GLOAD_LDS16(g, l) __builtin_amdgcn_global_load_lds(                    \
    (const __attribute__((address_space(1))) void*)(g),                        \
    (__attribute__((address_space(3))) void*)(l), 16, 0, 0)

__device__ inline unsigned transScore(float s) {
    unsigned u = __float_as_uint(s);
    return u ^ ((unsigned)((int)u >> 31) | 0x80000000u);   // order-preserving
}
__device__ inline float untransScore(unsigned u) {
    return (u & 0x80000000u) ? __uint_as_float(u ^ 0x80000000u)
                             : __uint_as_float(~u);
}

// prep: c2 + fp32->fp16 codebook + all workspace init. grid K x 64.
__global__ void prep_kernel(const float* __restrict__ cb, _Float16* __restrict__ cb16,
                            float* __restrict__ c2, char* __restrict__ ws) {
    int k = blockIdx.x, lane = threadIdx.x;
    float4 v = ((const float4*)(cb + (long)k * D))[lane];
    float s = v.x * v.x + v.y * v.y + v.z * v.z + v.w * v.w;
    for (int off = 32; off; off >>= 1) s += __shfl_xor(s, off);
    if (lane == 0) c2[k] = s;
    union { _Float16 h[4]; unsigned long long u; } t;
    t.h[0] = (_Float16)v.x; t.h[1] = (_Float16)v.y;
    t.h[2] = (_Float16)v.z; t.h[3] = (_Float16)v.w;
    *(unsigned long long*)(cb16 + (long)k * D + lane * 4) = t.u;
    if (k < N / 64) ((unsigned long long*)(ws + WS_RES))[k * 64 + lane] = ~0ull;
    if (lane == 0) ((int*)(ws + WS_CNTS))[k] = 0;
    if (k == 0 && lane == 0) ((unsigned*)(ws + WS_CNT))[0] = 0u;
}

// ---------------- fp16 MFMA distance GEMM with top-2 tracking ----------------
__global__ __launch_bounds__(GT, 4) void gemm_kernel(
        const float* __restrict__ z, const _Float16* __restrict__ cb16,
        const float* __restrict__ c2, ulonglong2* __restrict__ tops) {
    __shared__ _Float16 As[BMt * 256];          // 64 KB, swizzled
    __shared__ _Float16 Bs[2][BNt * 32];        // 2 x 8 KB, swizzled
    // total 81920 B exactly -> 2 blocks/CU. Top2 merge arrays union into Bs.

    const int tid = threadIdx.x;
    const int lane = tid & 63;
    const int wave = tid >> 6;                  // 8 waves: 2(M) x 4(N)
    const int wm = wave >> 2, wn = wave & 3;
    const long rowBase = (long)blockIdx.x * BMt;
    const int kbase = blockIdx.y * (K / KSPLIT);

    // ---- stage A (z rows) once: fp32 -> fp16, swizzled (validated layout) ----
    for (int i = 0; i < 8; ++i) {
        int id = tid + i * GT;                  // 4096 chunks of 8 floats
        int r = id >> 5, dseg = (id & 31) * 8;
        const float4* src = (const float4*)(z + (rowBase + r) * D + dseg);
        float4 v0 = src[0], v1 = src[1];
        union { _Float16 h[8]; ulonglong2 u; } t;
        t.h[0] = (_Float16)v0.x; t.h[1] = (_Float16)v0.y;
        t.h[2] = (_Float16)v0.z; t.h[3] = (_Float16)v0.w;
        t.h[4] = (_Float16)v1.x; t.h[5] = (_Float16)v1.y;
        t.h[6] = (_Float16)v1.z; t.h[7] = (_Float16)v1.w;
        int byte = (r * 256 + dseg) * 2;
        byte ^= (r & 7) << 4;
        *(ulonglong2*)((char*)As + byte) = t.u;
    }

    // ---- per-thread B-staging slot: inverse of the LDS read swizzle ----
    int bc, bt;
    {
        int h = tid >> 3, rr = tid & 7;
        bc = 2 * h; bt = rr ^ (bc & 7);
        if (bt & 4) { bc++; bt = (rr ^ (bc & 7)) & 3; }
    }
    char* ldsB0 = (char*)&Bs[0][0] + tid * 16;
    char* ldsB1 = (char*)&Bs[1][0] + tid * 16;

    // B chunk 0 (kb=0, dcI=0)
    GLOAD_LDS16(cb16 + ((long)(kbase + bc) << 8) + bt * 8, ldsB0);
    __syncthreads();                            // drains vmcnt + LDS writes

    // per-thread A/B frag byte offsets. A: xor applied AFTER adding dc.
    int aBase[4], aSwz[4], bOff[2];
#pragma unroll
    for (int fr = 0; fr < 4; ++fr) {
        int r = wm * 64 + fr * 16 + (lane & 15);
        aBase[fr] = r * 512 + (lane >> 4) * 16;
        aSwz[fr] = (r & 7) << 4;
    }
#pragma unroll
    for (int fc = 0; fc < 2; ++fc) {
        int c = wn * 32 + fc * 16 + (lane & 15);
        int byte = c * 64 + (lane >> 4) * 16;
        bOff[fc] = byte ^ ((c & 7) << 4);
    }

    f32x4 acc[4][2];
    float bV[16], bT2[16];
    int bI[16];
#pragma unroll
    for (int s = 0; s < 16; ++s) { bV[s] = 3.4e38f; bT2[s] = 3.4e38f; bI[s] = 0; }
    float c2v[2];

    const int NCH = (K / KSPLIT / BNt) * 8;      // 256 chunks
    int cur = 0;
    for (int j = 0; j < NCH; ++j) {
        const int kb = j >> 3, dcI = j & 7, dc = dcI * 32;
        // stage next chunk direct-to-LDS
        if (j + 1 < NCH) {
            int jj = j + 1;
            const _Float16* src = cb16
                + ((long)(kbase + (jj >> 3) * BNt + bc) << 8)
                + (jj & 7) * 32 + bt * 8;
            GLOAD_LDS16(src, cur ? ldsB0 : ldsB1);
        }
        if (dcI == 0) {
#pragma unroll
            for (int a = 0; a < 4; ++a)
#pragma unroll
                for (int b = 0; b < 2; ++b) acc[a][b] = (f32x4)0.f;
#pragma unroll
            for (int fc = 0; fc < 2; ++fc)
                c2v[fc] = c2[kbase + kb * BNt + wn * 32 + fc * 16 + (lane & 15)];
        }
        f16x8 aF[4], bF[2];
#pragma unroll
        for (int fr = 0; fr < 4; ++fr)
            aF[fr] = *(const f16x8*)((const char*)As +
                        ((aBase[fr] + dc * 2) ^ aSwz[fr]));
#pragma unroll
        for (int fc = 0; fc < 2; ++fc)
            bF[fc] = *(const f16x8*)((const char*)&Bs[cur][0] + bOff[fc]);
#pragma unroll
        for (int fr = 0; fr < 4; ++fr)
#pragma unroll
            for (int fc = 0; fc < 2; ++fc)
                acc[fr][fc] = __builtin_amdgcn_mfma_f32_16x16x32_f16(
                    aF[fr], bF[fc], acc[fr][fc], 0, 0, 0);
        if (dcI == 7) {
            // score + float top-2 (ties covered by DELTA rescore)
#pragma unroll
            for (int fc = 0; fc < 2; ++fc) {
                int gcol = kbase + kb * BNt + wn * 32 + fc * 16 + (lane & 15);
#pragma unroll
                for (int fr = 0; fr < 4; ++fr)
#pragma unroll
                    for (int r = 0; r < 4; ++r) {
                        float s = fmaf(-2.f, acc[fr][fc][r], c2v[fc]);
                        int slot = fr * 4 + r;
                        float t1o = bV[slot];
                        bT2[slot] = fminf(bT2[slot], fmaxf(s, t1o));
                        bool lt = s < t1o;
                        bV[slot] = lt ? s : t1o;
                        bI[slot] = lt ? gcol : bI[slot];
                    }
            }
        }
        __syncthreads();             // drain stage loads; guard Bs reuse
        cur ^= 1;
    }

    // intra-wave top2 merge over the 16 lanes sharing each row (float domain)
#pragma unroll
    for (int m = 1; m < 16; m <<= 1) {
#pragma unroll
        for (int s = 0; s < 16; ++s) {
            float ov = __shfl_xor(bV[s], m);
            int   oi = __shfl_xor(bI[s], m);
            float o2 = __shfl_xor(bT2[s], m);
            float nt2 = fminf(fminf(bT2[s], o2), fmaxf(bV[s], ov));
            bool take = ov < bV[s];
            bV[s] = take ? ov : bV[s];
            bI[s] = take ? oi : bI[s];
            bT2[s] = nt2;
        }
    }
    // cross-wave (4 wn waves) top2 merge via LDS atomicMin-displacement,
    // arrays unioned into Bs (K-loop done, last barrier passed).
    unsigned long long* L1 = (unsigned long long*)&Bs[0][0];   // 1 KB
    unsigned* L2s = (unsigned*)(L1 + BMt);                     // 512 B
    if (tid < BMt) { L1[tid] = ~0ull; L2s[tid] = 0xFFFFFFFFu; }
    __syncthreads();
    if ((lane & 15) == 0) {
#pragma unroll
        for (int s = 0; s < 16; ++s) {
            int row = wm * 64 + (s >> 2) * 16 + (lane >> 4) * 4 + (s & 3);
            unsigned long long t1 =
                ((unsigned long long)transScore(bV[s]) << 32) | (unsigned)bI[s];
            unsigned long long old1 = atomicMin(&L1[row], t1);
            unsigned long long cand = t1 < old1 ? old1 : t1;
            atomicMin(&L2s[row], (unsigned)(cand >> 32));
            atomicMin(&L2s[row], transScore(bT2[s]));
        }
    }
    __syncthreads();
    if (tid < BMt) {
        ulonglong2 v; v.x = L1[tid]; v.y = (unsigned long long)L2s[tid];
        tops[(rowBase + tid) * KSPLIT + blockIdx.y] = v;
    }
}

// merge + histogram of confidently-resolved rows
__global__ void merge_kernel(const ulonglong2* __restrict__ tops,
                             float* __restrict__ out, int* __restrict__ idxArr,
                             unsigned* __restrict__ flagCount,
                             int* __restrict__ flagRows, int* __restrict__ counts) {
    int row = blockIdx.x * 256 + threadIdx.x;
    ulonglong2 a = tops[row * 2], b = tops[row * 2 + 1];
    unsigned long long t1 = a.x < b.x ? a.x : b.x;
    unsigned a1 = (unsigned)(a.x >> 32), b1 = (unsigned)(b.x >> 32);
    unsigned mx = a1 > b1 ? a1 : b1;
    unsigned t2 = (unsigned)a.y < (unsigned)b.y ? (unsigned)a.y : (unsigned)b.y;
    t2 = t2 < mx ? t2 : mx;
    float s1 = untransScore((unsigned)(t1 >> 32));
    float s2 = untransScore(t2);
    int idx = (int)(t1 & 0xFFFFFFFFull);
    idxArr[row] = idx;
    out[IDX_OFF + row] = (float)idx;
    if (s2 - s1 <= DELTA) {
        unsigned p = atomicAdd(flagCount, 1u);
        flagRows[p] = row;
    } else {
        atomicAdd(&counts[idx], 1);
    }
}

// exact fp32 rescore of flagged rows. Grid (RSL slots, RKS splits of RBN codes).
// One 64x128 tile per group-iteration; 4x4 thread tile; R2-style staging.
__global__ __launch_bounds__(512) void resolve_kernel(
        const float* __restrict__ z, const float* __restrict__ cb,
        const float* __restrict__ c2, const unsigned* __restrict__ flagCount,
        const int* __restrict__ flagRows, unsigned long long* __restrict__ resolved) {
    __shared__ float zT[32][RBM + 4];       // [d][row], 8.7 KB
    __shared__ float cT[32][RBN + 4];       // [d][code], 16.9 KB
    __shared__ float c2s[RBN];
    __shared__ int rid[RBM];

    const int cnt = (int)*flagCount;
    const int tid = threadIdx.x;
    const int tx = tid & 31, ty = tid >> 5;     // ty 0..15
    const int rbase = ty * 4, cbase = tx * 4;
    const int k0 = blockIdx.y * RBN;

    if (tid < RBN) c2s[tid] = c2[k0 + tid];

    for (int g = blockIdx.x; g * RBM < cnt; g += RSL) {
        __syncthreads();                    // previous group fully done
        if (tid < RBM) {
            int fi = g * RBM + tid;
            rid[tid] = flagRows[fi < cnt ? fi : cnt - 1];   // pad = dup (harmless)
        }

        float acc[4][4];
#pragma unroll
        for (int r = 0; r < 4; ++r)
#pragma unroll
            for (int c = 0; c < 4; ++c) acc[r][c] = 0.f;

        for (int dc = 0; dc < D; dc += 32) {
            __syncthreads();                // rid visible; prev reads done
            // stage z: 64 rows x 8 float4 = 512 slots (1 per thread)
            {
                int row = tid >> 3, dq = tid & 7;
                float4 v = *(const float4*)(z + (long)rid[row] * D + dc + dq * 4);
                zT[dq * 4 + 0][row] = v.x; zT[dq * 4 + 1][row] = v.y;
                zT[dq * 4 + 2][row] = v.z; zT[dq * 4 + 3][row] = v.w;
            }
            // stage cT: 128 codes x 8 float4 = 1024 slots (2 per thread)
#pragma unroll
            for (int i = 0; i < 2; ++i) {
                int id = tid + i * 512;
                int c = id >> 3, dq = id & 7;
                float4 w = *(const float4*)(cb + (long)(k0 + c) * D + dc + dq * 4);
                cT[dq * 4 + 0][c] = w.x; cT[dq * 4 + 1][c] = w.y;
                cT[dq * 4 + 2][c] = w.z; cT[dq * 4 + 3][c] = w.w;
            }
            __syncthreads();
#pragma unroll
            for (int d = 0; d < 32; ++d) {
                float a[4], b[4];
                *(float4*)&a[0] = *(const float4*)&zT[d][rbase];   // bcast x2
                *(float4*)&b[0] = *(const float4*)&cT[d][cbase];
#pragma unroll
                for (int r = 0; r < 4; ++r)
#pragma unroll
                    for (int c = 0; c < 4; ++c)
                        acc[r][c] = fmaf(a[r], b[c], acc[r][c]);
            }
        }
        // score + per-row best over this block's 128 codes
        float bestV[4]; int bestI[4];
#pragma unroll
        for (int r = 0; r < 4; ++r) { bestV[r] = 3.4e38f; bestI[r] = 0; }
#pragma unroll
        for (int c = 0; c < 4; ++c) {
            float cc = c2s[cbase + c];
            int col = k0 + cbase + c;
#pragma unroll
            for (int r = 0; r < 4; ++r) {
                float score = fmaf(-2.f, acc[r][c], cc);
                if (score < bestV[r]) { bestV[r] = score; bestI[r] = col; }
            }
        }
        // reduce over the 32 tx lanes (codes); first-index ties
#pragma unroll
        for (int off = 16; off; off >>= 1) {
#pragma unroll
            for (int r = 0; r < 4; ++r) {
                float ov = __shfl_xor(bestV[r], off);
                int   oi = __shfl_xor(bestI[r], off);
                if (ov < bestV[r] || (ov == bestV[r] && oi < bestI[r])) {
                    bestV[r] = ov; bestI[r] = oi;
                }
            }
        }
        if (tx == 0) {
#pragma unroll
            for (int r = 0; r < 4; ++r) {
                unsigned long long u =
                    ((unsigned long long)transScore(bestV[r]) << 32)
                    | (unsigned)bestI[r];
                atomicMin(&resolved[rid[rbase + r]], u);
            }
        }
    }
}

// writeback + histogram of flagged rows
__global__ void writeback_kernel(const unsigned* __restrict__ flagCount,
                                 const int* __restrict__ flagRows,
                                 const unsigned long long* __restrict__ resolved,
                                 int* __restrict__ idxArr, float* __restrict__ out,
                                 int* __restrict__ counts) {
    int i = blockIdx.x * 256 + threadIdx.x;
    if (i < (int)*flagCount) {
        int row = flagRows[i];
        int idx = (int)(resolved[row] & 0xFFFFFFFFull);
        idxArr[row] = idx;
        out[IDX_OFF + row] = (float)idx;
        atomicAdd(&counts[idx], 1);
    }
}

// single block: exclusive scan of counts -> cursor, CS output, n scalar
__global__ __launch_bounds__(1024) void scan_kernel(
        const int* __restrict__ counts, const float* __restrict__ cs,
        int* __restrict__ cursor, float* __restrict__ out,
        float* __restrict__ nacc) {
    __shared__ int wtot[16];
    __shared__ float csred[16];
    int tid = threadIdx.x;
    int lane = tid & 63, w = tid >> 6;
    int base = tid * 8;                 // 8192 / 1024
    int4 c0 = ((const int4*)(counts + base))[0];
    int4 c1 = ((const int4*)(counts + base))[1];
    float4 f0 = ((const float4*)(cs + base))[0];
    float4 f1 = ((const float4*)(cs + base))[1];
    int local[8] = {c0.x, c0.y, c0.z, c0.w, c1.x, c1.y, c1.z, c1.w};
    float csv[8] = {f0.x, f0.y, f0.z, f0.w, f1.x, f1.y, f1.z, f1.w};
    int sum = 0; float csum = 0.f;
#pragma unroll
    for (int i = 0; i < 8; ++i) { sum += local[i]; csum += csv[i]; }
    // wave-inclusive scan of per-thread sums
    int inc = sum;
#pragma unroll
    for (int off = 1; off < 64; off <<= 1) {
        int v = __shfl_up(inc, off);
        if (lane >= off) inc += v;
    }
    // cs partial reduce per wave
    for (int off = 32; off; off >>= 1) csum += __shfl_xor(csum, off);
    if (lane == 63) wtot[w] = inc;
    if (lane == 0) csred[w] = csum;
    __syncthreads();
    // wave 0 scans the 16 wave totals (exclusive)
    if (w == 0 && lane < 16) {
        int v = wtot[lane];
        int s2 = v;
#pragma unroll
        for (int off = 1; off < 16; off <<= 1) {
            int t = __shfl_up(s2, off);
            if (lane >= off) s2 += t;
        }
        wtot[lane] = s2 - v;            // exclusive wave offset
    }
    __syncthreads();
    int run = wtot[w] + (inc - sum);    // exclusive prefix of this thread chunk
#pragma unroll
    for (int i = 0; i < 8; ++i) {
        cursor[base + i] = run;
        out[CS_OFF + base + i] = csv[i] * DECAY + OMD * (float)local[i];
        run += local[i];
    }
    if (tid == 0) {
        float t = 0.f;
#pragma unroll
        for (int i = 0; i < 16; ++i) t += csred[i];
        *nacc = t * DECAY + OMD * (float)N;   // sum(counts) == N exactly
    }
}

// scatter (counting-sort placement) fused with quantized-gather copy
__global__ __launch_bounds__(512) void scatter_quantize_kernel(
        const float* __restrict__ cb, const int* __restrict__ idxArr,
        int* __restrict__ cursor, int* __restrict__ sorted,
        float* __restrict__ out) {
    int tid = threadIdx.x;
    int r = tid >> 2, seg = tid & 3;
    int gRow = blockIdx.x * 128 + r;
    int code = idxArr[gRow];
    if (seg == 0) {
        int pos = atomicAdd(&cursor[code], 1);
        sorted[pos] = gRow;
    }
    const float4* cbv = (const float4*)(cb + (long)code * D + seg * 64);
    float4* qv = (float4*)(out + Q_OFF + (long)gRow * D + seg * 64);
#pragma unroll 4
    for (int i = 0; i < 16; ++i) qv[i] = cbv[i];
}

// one wave per code: gather-sum its rows, write new_embedding_avg AND
// new_codebook (finalize folded in).
__global__ __launch_bounds__(256) void gather_sum_kernel(
        const float* __restrict__ z, const float* __restrict__ emb,
        const int* __restrict__ sorted, const int* __restrict__ cursor,
        const int* __restrict__ counts, const float* __restrict__ nacc,
        float* __restrict__ out) {
    int k = blockIdx.x * 4 + (threadIdx.x >> 6);
    int lane = threadIdx.x & 63;
    int cnt = counts[k];
    int start = cursor[k] - cnt;        // cursor was advanced by scatter
    float4 s = {0.f, 0.f, 0.f, 0.f};
    for (int i = 0; i < cnt; ++i) {
        int row = sorted[start + i];
        float4 v = *(const float4*)(z + (long)row * D + lane * 4);
        s.x += v.x; s.y += v.y; s.z += v.z; s.w += v.w;
    }
    float4 e = *(const float4*)(emb + (long)k * D + lane * 4);
    float4 o;
    o.x = e.x * DECAY + OMD * s.x;
    o.y = e.y * DECAY + OMD * s.y;
    o.z = e.z * DECAY + OMD * s.z;
    o.w = e.w * DECAY + OMD * s.w;
    *(float4*)(out + EMB_OFF + (long)k * D + lane * 4) = o;
    float n = *nacc;
    float ncs = out[CS_OFF + k];
    float smoothed = (ncs + EPS) / (n + (float)K * EPS) * n;
    float4 q;
    q.x = o.x / smoothed; q.y = o.y / smoothed;
    q.z = o.z / smoothed; q.w = o.w / smoothed;
    *(float4*)(out + CB_OFF + (long)k * D + lane * 4) = q;
}

extern "C" void kernel_launch(void* const* d_in, const int* in_sizes, int n_in,
                              void* d_out, int out_size, void* d_ws, size_t ws_size,
                              hipStream_t stream) {
    const float* z   = (const float*)d_in[0];
    const float* cb  = (const float*)d_in[1];
    const float* emb = (const float*)d_in[2];
    const float* cs  = (const float*)d_in[3];
    float* out = (float*)d_out;
    char* ws = (char*)d_ws;

    ulonglong2* tops = (ulonglong2*)(ws + WS_TOPS);
    unsigned long long* resolved = (unsigned long long*)(ws + WS_RES);
    int* idxArr = (int*)(ws + WS_IDX);
    float* c2 = (float*)(ws + WS_C2);
    int* flagRows = (int*)(ws + WS_FLAG);
    unsigned* flagCount = (unsigned*)(ws + WS_CNT);
    float* nacc = (float*)(ws + WS_CNT) + 1;
    int* counts = (int*)(ws + WS_CNTS);
    int* cursor = (int*)(ws + WS_CUR);
    int* sorted = (int*)(ws + WS_SORT);
    _Float16* cb16 = (_Float16*)(out + Q_OFF);   // scratch in quantized region

    prep_kernel<<<K, 64, 0, stream>>>(cb, cb16, c2, ws);
    dim3 ggrid(N / BMt, KSPLIT);
    gemm_kernel<<<ggrid, GT, 0, stream>>>(z, cb16, c2, tops);
    merge_kernel<<<N / 256, 256, 0, stream>>>(tops, out, idxArr, flagCount,
                                              flagRows, counts);
    dim3 rgrid(RSL, RKS);
    resolve_kernel<<<rgrid, 512, 0, stream>>>(z, cb, c2, flagCount, flagRows, resolved);
    writeback_kernel<<<N / 256, 256, 0, stream>>>(flagCount, flagRows, resolved,
                                                  idxArr, out, counts);
    scan_kernel<<<1, 1024, 0, stream>>>(counts, cs, cursor, out, nacc);
    scatter_quantize_kernel<<<N / 128, 512, 0, stream>>>(cb, idxArr, cursor,
                                                         sorted, out);
    gather_sum_kernel<<<K / 4, 256, 0, stream>>>(z, emb, sorted, cursor, counts,
                                                 nacc, out);
}

// Round 15
// 549.043 us; speedup vs baseline: 1.2227x; 1.0106x over previous
//
#include <hip/hip_runtime.h>

// EMA codebook update (VQ-VAE), MI355X. fp16-MFMA distance filter + exact
// fp32 rescore for near-ties. N=32768, K=8192, D=256.
// R15: gemm wave tile 64x32 -> 64x64 (4 waves, GT=256): LDS-read traffic
//      per FLOP cut 1.5x (the measured bottleneck: 96KB/chunk/CU at
//      85-128 B/cyc ~ the 963-cyc chunk period). A-swizzle widened to
//      (r&15)<<4 both sides (kills 2-way aF conflict). 2 blocks/CU kept.
//      Tail identical to R12/R14.

#define DECAY 0.99f
#define OMD 0.01f
#define EPS 1e-5f
#define DELTA 0.3f

constexpr int N = 32768, K = 8192, D = 256;
constexpr int KSPLIT = 2;               // gemm grid: 256 row-tiles x 2 code-splits
constexpr int BMt = 128, BNt = 128;     // gemm tile
constexpr int GT = 256;                 // gemm threads (4 waves: 2M x 2N, 64x64)

// resolve config
constexpr int RBM = 64;                 // flagged rows per group
constexpr int RBN = 128;                // codes per K-split
constexpr int RKS = 64;                 // K splits
constexpr int RSL = 16;                 // group slots

typedef _Float16 f16x8 __attribute__((ext_vector_type(8)));
typedef float f32x4 __attribute__((ext_vector_type(4)));

// d_out layout (floats, reference return order)
constexpr long Q_OFF   = 0;
constexpr long IDX_OFF = (long)N * D;
constexpr long CB_OFF  = IDX_OFF + N;
constexpr long EMB_OFF = CB_OFF + (long)K * D;
constexpr long CS_OFF  = EMB_OFF + (long)K * D;

// ws layout (bytes)
constexpr long WS_TOPS = 0;                          // ulonglong2[N*KSPLIT]
constexpr long WS_RES  = WS_TOPS + (long)N * 2 * 16; // u64[N] resolved
constexpr long WS_IDX  = WS_RES + (long)N * 8;       // int[N]
constexpr long WS_C2   = WS_IDX + (long)N * 4;       // float[K]
constexpr long WS_FLAG = WS_C2 + (long)K * 4;        // int[N] flagged rows
constexpr long WS_CNT  = WS_FLAG + (long)N * 4;      // [0] u32 count, [1] f32 nacc
constexpr long WS_CNTS = WS_CNT + 8;                 // int[K] histogram
constexpr long WS_CUR  = WS_CNTS + (long)K * 4;      // int[K] scan/cursor
constexpr long WS_SORT = WS_CUR + (long)K * 4;       // int[N] rows sorted by code

#define GLOAD_LDS16(g, l) __builtin_amdgcn_global_load_lds(                    \
    (const __attribute__((address_space(1))) void*)(g),                        \
    (__attribute__((address_space(3))) void*)(l), 16, 0, 0)

__device__ inline unsigned transScore(float s) {
    unsigned u = __float_as_uint(s);
    return u ^ ((unsigned)((int)u >> 31) | 0x80000000u);   // order-preserving
}
__device__ inline float untransScore(unsigned u) {
    return (u & 0x80000000u) ? __uint_as_float(u ^ 0x80000000u)
                             : __uint_as_float(~u);
}

// prep: c2 + fp32->fp16 codebook + all workspace init. grid K x 64.
__global__ void prep_kernel(const float* __restrict__ cb, _Float16* __restrict__ cb16,
                            float* __restrict__ c2, char* __restrict__ ws) {
    int k = blockIdx.x, lane = threadIdx.x;
    float4 v = ((const float4*)(cb + (long)k * D))[lane];
    float s = v.x * v.x + v.y * v.y + v.z * v.z + v.w * v.w;
    for (int off = 32; off; off >>= 1) s += __shfl_xor(s, off);
    if (lane == 0) c2[k] = s;
    union { _Float16 h[4]; unsigned long long u; } t;
    t.h[0] = (_Float16)v.x; t.h[1] = (_Float16)v.y;
    t.h[2] = (_Float16)v.z; t.h[3] = (_Float16)v.w;
    *(unsigned long long*)(cb16 + (long)k * D + lane * 4) = t.u;
    if (k < N / 64) ((unsigned long long*)(ws + WS_RES))[k * 64 + lane] = ~0ull;
    if (lane == 0) ((int*)(ws + WS_CNTS))[k] = 0;
    if (k == 0 && lane == 0) ((unsigned*)(ws + WS_CNT))[0] = 0u;
}

// B-staging slot q -> (code, 8-elem group) inverse of the LDS read swizzle
__device__ inline void bslot(int q, int& bc, int& bt) {
    int h = q >> 3, rr = q & 7;
    bc = 2 * h; bt = rr ^ (bc & 7);
    if (bt & 4) { bc++; bt = (rr ^ (bc & 7)) & 3; }
}

// ---------------- fp16 MFMA distance GEMM with top-2 tracking ----------------
__global__ __launch_bounds__(GT, 2) void gemm_kernel(
        const float* __restrict__ z, const _Float16* __restrict__ cb16,
        const float* __restrict__ c2, ulonglong2* __restrict__ tops) {
    __shared__ _Float16 As[BMt * 256];          // 64 KB, swizzled (r&15)
    __shared__ _Float16 Bs[2][BNt * 32];        // 2 x 8 KB, swizzled
    // total 81920 B exactly -> 2 blocks/CU. Top2 merge arrays union into Bs.

    const int tid = threadIdx.x;
    const int lane = tid & 63;
    const int wave = tid >> 6;                  // 4 waves: 2(M) x 2(N)
    const int wm = wave >> 1, wn = wave & 1;
    const long rowBase = (long)blockIdx.x * BMt;
    const int kbase = blockIdx.y * (K / KSPLIT);

    // ---- stage A (z rows) once: fp32 -> fp16, swizzled ----
    for (int i = 0; i < 16; ++i) {
        int id = tid + i * GT;                  // 4096 chunks of 8 floats
        int r = id >> 5, dseg = (id & 31) * 8;
        const float4* src = (const float4*)(z + (rowBase + r) * D + dseg);
        float4 v0 = src[0], v1 = src[1];
        union { _Float16 h[8]; ulonglong2 u; } t;
        t.h[0] = (_Float16)v0.x; t.h[1] = (_Float16)v0.y;
        t.h[2] = (_Float16)v0.z; t.h[3] = (_Float16)v0.w;
        t.h[4] = (_Float16)v1.x; t.h[5] = (_Float16)v1.y;
        t.h[6] = (_Float16)v1.z; t.h[7] = (_Float16)v1.w;
        int byte = (r * 256 + dseg) * 2;
        byte ^= (r & 15) << 4;                  // widened swizzle (both sides)
        *(ulonglong2*)((char*)As + byte) = t.u;
    }

    // ---- per-thread B-staging slots (2 per thread) ----
    int bc0, bt0, bc1, bt1;
    bslot(tid, bc0, bt0);
    bslot(tid + 256, bc1, bt1);
    char* ldsB0a = (char*)&Bs[0][0] + tid * 16;
    char* ldsB0b = (char*)&Bs[0][0] + (tid + 256) * 16;
    char* ldsB1a = (char*)&Bs[1][0] + tid * 16;
    char* ldsB1b = (char*)&Bs[1][0] + (tid + 256) * 16;

    // B chunk 0 (kb=0, dcI=0)
    GLOAD_LDS16(cb16 + ((long)(kbase + bc0) << 8) + bt0 * 8, ldsB0a);
    GLOAD_LDS16(cb16 + ((long)(kbase + bc1) << 8) + bt1 * 8, ldsB0b);
    __syncthreads();                            // drains vmcnt + LDS writes

    // per-thread A/B frag byte offsets. A: xor applied AFTER adding dc.
    int aBase[4], aSwz[4], bOff[4];
#pragma unroll
    for (int fr = 0; fr < 4; ++fr) {
        int r = wm * 64 + fr * 16 + (lane & 15);
        aBase[fr] = r * 512 + (lane >> 4) * 16;
        aSwz[fr] = (r & 15) << 4;
    }
#pragma unroll
    for (int fc = 0; fc < 4; ++fc) {
        int c = wn * 64 + fc * 16 + (lane & 15);
        int byte = c * 64 + (lane >> 4) * 16;
        bOff[fc] = byte ^ ((c & 7) << 4);
    }

    f32x4 acc[4][4];
    float bV[16], bT2[16];
    int bI[16];
#pragma unroll
    for (int s = 0; s < 16; ++s) { bV[s] = 3.4e38f; bT2[s] = 3.4e38f; bI[s] = 0; }
    float c2v[4];

    const int NCH = (K / KSPLIT / BNt) * 8;      // 256 chunks
    int cur = 0;
    for (int j = 0; j < NCH; ++j) {
        const int kb = j >> 3, dcI = j & 7, dc = dcI * 32;
        // stage next chunk direct-to-LDS
        if (j + 1 < NCH) {
            int jj = j + 1;
            long cbase2 = (long)(kbase + (jj >> 3) * BNt);
            int doff = (jj & 7) * 32;
            GLOAD_LDS16(cb16 + ((cbase2 + bc0) << 8) + doff + bt0 * 8,
                        cur ? ldsB0a : ldsB1a);
            GLOAD_LDS16(cb16 + ((cbase2 + bc1) << 8) + doff + bt1 * 8,
                        cur ? ldsB0b : ldsB1b);
        }
        if (dcI == 0) {
#pragma unroll
            for (int a = 0; a < 4; ++a)
#pragma unroll
                for (int b = 0; b < 4; ++b) acc[a][b] = (f32x4)0.f;
#pragma unroll
            for (int fc = 0; fc < 4; ++fc)
                c2v[fc] = c2[kbase + kb * BNt + wn * 64 + fc * 16 + (lane & 15)];
        }
        f16x8 aF[4], bF[4];
#pragma unroll
        for (int fr = 0; fr < 4; ++fr)
            aF[fr] = *(const f16x8*)((const char*)As +
                        ((aBase[fr] + dc * 2) ^ aSwz[fr]));
#pragma unroll
        for (int fc = 0; fc < 4; ++fc)
            bF[fc] = *(const f16x8*)((const char*)&Bs[cur][0] + bOff[fc]);
#pragma unroll
        for (int fr = 0; fr < 4; ++fr)
#pragma unroll
            for (int fc = 0; fc < 4; ++fc)
                acc[fr][fc] = __builtin_amdgcn_mfma_f32_16x16x32_f16(
                    aF[fr], bF[fc], acc[fr][fc], 0, 0, 0);
        if (dcI == 7) {
            // score + float top-2 (ties covered by DELTA rescore)
#pragma unroll
            for (int fc = 0; fc < 4; ++fc) {
                int gcol = kbase + kb * BNt + wn * 64 + fc * 16 + (lane & 15);
#pragma unroll
                for (int fr = 0; fr < 4; ++fr)
#pragma unroll
                    for (int r = 0; r < 4; ++r) {
                        float s = fmaf(-2.f, acc[fr][fc][r], c2v[fc]);
                        int slot = fr * 4 + r;
                        float t1o = bV[slot];
                        bT2[slot] = fminf(bT2[slot], fmaxf(s, t1o));
                        bool lt = s < t1o;
                        bV[slot] = lt ? s : t1o;
                        bI[slot] = lt ? gcol : bI[slot];
                    }
            }
        }
        __syncthreads();             // drain stage loads; guard Bs reuse
        cur ^= 1;
    }

    // intra-wave top2 merge over the 16 lanes sharing each row (float domain)
#pragma unroll
    for (int m = 1; m < 16; m <<= 1) {
#pragma unroll
        for (int s = 0; s < 16; ++s) {
            float ov = __shfl_xor(bV[s], m);
            int   oi = __shfl_xor(bI[s], m);
            float o2 = __shfl_xor(bT2[s], m);
            float nt2 = fminf(fminf(bT2[s], o2), fmaxf(bV[s], ov));
            bool take = ov < bV[s];
            bV[s] = take ? ov : bV[s];
            bI[s] = take ? oi : bI[s];
            bT2[s] = nt2;
        }
    }
    // cross-wave (2 wn waves) top2 merge via LDS atomicMin-displacement,
    // arrays unioned into Bs (K-loop done, last barrier passed).
    unsigned long long* L1 = (unsigned long long*)&Bs[0][0];   // 1 KB
    unsigned* L2s = (unsigned*)(L1 + BMt);                     // 512 B
    if (tid < BMt) { L1[tid] = ~0ull; L2s[tid] = 0xFFFFFFFFu; }
    __syncthreads();
    if ((lane & 15) == 0) {
#pragma unroll
        for (int s = 0; s < 16; ++s) {
            int row = wm * 64 + (s >> 2) * 16 + (lane >> 4) * 4 + (s & 3);
            unsigned long long t1 =
                ((unsigned long long)transScore(bV[s]) << 32) | (unsigned)bI[s];
            unsigned long long old1 = atomicMin(&L1[row], t1);
            unsigned long long cand = t1 < old1 ? old1 : t1;
            atomicMin(&L2s[row], (unsigned)(cand >> 32));
            atomicMin(&L2s[row], transScore(bT2[s]));
        }
    }
    __syncthreads();
    if (tid < BMt) {
        ulonglong2 v; v.x = L1[tid]; v.y = (unsigned long long)L2s[tid];
        tops[(rowBase + tid) * KSPLIT + blockIdx.y] = v;
    }
}

// merge + histogram of confidently-resolved rows
__global__ void merge_kernel(const ulonglong2* __restrict__ tops,
                             float* __restrict__ out, int* __restrict__ idxArr,
                             unsigned* __restrict__ flagCount,
                             int* __restrict__ flagRows, int* __restrict__ counts) {
    int row = blockIdx.x * 256 + threadIdx.x;
    ulonglong2 a = tops[row * 2], b = tops[row * 2 + 1];
    unsigned long long t1 = a.x < b.x ? a.x : b.x;
    unsigned a1 = (unsigned)(a.x >> 32), b1 = (unsigned)(b.x >> 32);
    unsigned mx = a1 > b1 ? a1 : b1;
    unsigned t2 = (unsigned)a.y < (unsigned)b.y ? (unsigned)a.y : (unsigned)b.y;
    t2 = t2 < mx ? t2 : mx;
    float s1 = untransScore((unsigned)(t1 >> 32));
    float s2 = untransScore(t2);
    int idx = (int)(t1 & 0xFFFFFFFFull);
    idxArr[row] = idx;
    out[IDX_OFF + row] = (float)idx;
    if (s2 - s1 <= DELTA) {
        unsigned p = atomicAdd(flagCount, 1u);
        flagRows[p] = row;
    } else {
        atomicAdd(&counts[idx], 1);
    }
}

// exact fp32 rescore of flagged rows. Grid (RSL slots, RKS splits of RBN codes).
__global__ __launch_bounds__(512) void resolve_kernel(
        const float* __restrict__ z, const float* __restrict__ cb,
        const float* __restrict__ c2, const unsigned* __restrict__ flagCount,
        const int* __restrict__ flagRows, unsigned long long* __restrict__ resolved) {
    __shared__ float zT[32][RBM + 4];       // [d][row], 8.7 KB
    __shared__ float cT[32][RBN + 4];       // [d][code], 16.9 KB
    __shared__ float c2s[RBN];
    __shared__ int rid[RBM];

    const int cnt = (int)*flagCount;
    const int tid = threadIdx.x;
    const int tx = tid & 31, ty = tid >> 5;     // ty 0..15
    const int rbase = ty * 4, cbase = tx * 4;
    const int k0 = blockIdx.y * RBN;

    if (tid < RBN) c2s[tid] = c2[k0 + tid];

    for (int g = blockIdx.x; g * RBM < cnt; g += RSL) {
        __syncthreads();                    // previous group fully done
        if (tid < RBM) {
            int fi = g * RBM + tid;
            rid[tid] = flagRows[fi < cnt ? fi : cnt - 1];   // pad = dup (harmless)
        }

        float acc[4][4];
#pragma unroll
        for (int r = 0; r < 4; ++r)
#pragma unroll
            for (int c = 0; c < 4; ++c) acc[r][c] = 0.f;

        for (int dc = 0; dc < D; dc += 32) {
            __syncthreads();                // rid visible; prev reads done
            // stage z: 64 rows x 8 float4 = 512 slots (1 per thread)
            {
                int row = tid >> 3, dq = tid & 7;
                float4 v = *(const float4*)(z + (long)rid[row] * D + dc + dq * 4);
                zT[dq * 4 + 0][row] = v.x; zT[dq * 4 + 1][row] = v.y;
                zT[dq * 4 + 2][row] = v.z; zT[dq * 4 + 3][row] = v.w;
            }
            // stage cT: 128 codes x 8 float4 = 1024 slots (2 per thread)
#pragma unroll
            for (int i = 0; i < 2; ++i) {
                int id = tid + i * 512;
                int c = id >> 3, dq = id & 7;
                float4 w = *(const float4*)(cb + (long)(k0 + c) * D + dc + dq * 4);
                cT[dq * 4 + 0][c] = w.x; cT[dq * 4 + 1][c] = w.y;
                cT[dq * 4 + 2][c] = w.z; cT[dq * 4 + 3][c] = w.w;
            }
            __syncthreads();
#pragma unroll
            for (int d = 0; d < 32; ++d) {
                float a[4], b[4];
                *(float4*)&a[0] = *(const float4*)&zT[d][rbase];   // bcast x2
                *(float4*)&b[0] = *(const float4*)&cT[d][cbase];
#pragma unroll
                for (int r = 0; r < 4; ++r)
#pragma unroll
                    for (int c = 0; c < 4; ++c)
                        acc[r][c] = fmaf(a[r], b[c], acc[r][c]);
            }
        }
        // score + per-row best over this block's 128 codes
        float bestV[4]; int bestI[4];
#pragma unroll
        for (int r = 0; r < 4; ++r) { bestV[r] = 3.4e38f; bestI[r] = 0; }
#pragma unroll
        for (int c = 0; c < 4; ++c) {
            float cc = c2s[cbase + c];
            int col = k0 + cbase + c;
#pragma unroll
            for (int r = 0; r < 4; ++r) {
                float score = fmaf(-2.f, acc[r][c], cc);
                if (score < bestV[r]) { bestV[r] = score; bestI[r] = col; }
            }
        }
        // reduce over the 32 tx lanes (codes); first-index ties
#pragma unroll
        for (int off = 16; off; off >>= 1) {
#pragma unroll
            for (int r = 0; r < 4; ++r) {
                float ov = __shfl_xor(bestV[r], off);
                int   oi = __shfl_xor(bestI[r], off);
                if (ov < bestV[r] || (ov == bestV[r] && oi < bestI[r])) {
                    bestV[r] = ov; bestI[r] = oi;
                }
            }
        }
        if (tx == 0) {
#pragma unroll
            for (int r = 0; r < 4; ++r) {
                unsigned long long u =
                    ((unsigned long long)transScore(bestV[r]) << 32)
                    | (unsigned)bestI[r];
                atomicMin(&resolved[rid[rbase + r]], u);
            }
        }
    }
}

// writeback + histogram of flagged rows
__global__ void writeback_kernel(const unsigned* __restrict__ flagCount,
                                 const int* __restrict__ flagRows,
                                 const unsigned long long* __restrict__ resolved,
                                 int* __restrict__ idxArr, float* __restrict__ out,
                                 int* __restrict__ counts) {
    int i = blockIdx.x * 256 + threadIdx.x;
    if (i < (int)*flagCount) {
        int row = flagRows[i];
        int idx = (int)(resolved[row] & 0xFFFFFFFFull);
        idxArr[row] = idx;
        out[IDX_OFF + row] = (float)idx;
        atomicAdd(&counts[idx], 1);
    }
}

// single block: exclusive scan of counts -> cursor, CS output, n scalar
__global__ __launch_bounds__(1024) void scan_kernel(
        const int* __restrict__ counts, const float* __restrict__ cs,
        int* __restrict__ cursor, float* __restrict__ out,
        float* __restrict__ nacc) {
    __shared__ int wtot[16];
    __shared__ float csred[16];
    int tid = threadIdx.x;
    int lane = tid & 63, w = tid >> 6;
    int base = tid * 8;                 // 8192 / 1024
    int4 c0 = ((const int4*)(counts + base))[0];
    int4 c1 = ((const int4*)(counts + base))[1];
    float4 f0 = ((const float4*)(cs + base))[0];
    float4 f1 = ((const float4*)(cs + base))[1];
    int local[8] = {c0.x, c0.y, c0.z, c0.w, c1.x, c1.y, c1.z, c1.w};
    float csv[8] = {f0.x, f0.y, f0.z, f0.w, f1.x, f1.y, f1.z, f1.w};
    int sum = 0; float csum = 0.f;
#pragma unroll
    for (int i = 0; i < 8; ++i) { sum += local[i]; csum += csv[i]; }
    // wave-inclusive scan of per-thread sums
    int inc = sum;
#pragma unroll
    for (int off = 1; off < 64; off <<= 1) {
        int v = __shfl_up(inc, off);
        if (lane >= off) inc += v;
    }
    // cs partial reduce per wave
    for (int off = 32; off; off >>= 1) csum += __shfl_xor(csum, off);
    if (lane == 63) wtot[w] = inc;
    if (lane == 0) csred[w] = csum;
    __syncthreads();
    // wave 0 scans the 16 wave totals (exclusive)
    if (w == 0 && lane < 16) {
        int v = wtot[lane];
        int s2 = v;
#pragma unroll
        for (int off = 1; off < 16; off <<= 1) {
            int t = __shfl_up(s2, off);
            if (lane >= off) s2 += t;
        }
        wtot[lane] = s2 - v;            // exclusive wave offset
    }
    __syncthreads();
    int run = wtot[w] + (inc - sum);    // exclusive prefix of this thread chunk
#pragma unroll
    for (int i = 0; i < 8; ++i) {
        cursor[base + i] = run;
        out[CS_OFF + base + i] = csv[i] * DECAY + OMD * (float)local[i];
        run += local[i];
    }
    if (tid == 0) {
        float t = 0.f;
#pragma unroll
        for (int i = 0; i < 16; ++i) t += csred[i];
        *nacc = t * DECAY + OMD * (float)N;   // sum(counts) == N exactly
    }
}

// scatter (counting-sort placement) fused with quantized-gather copy
__global__ __launch_bounds__(512) void scatter_quantize_kernel(
        const float* __restrict__ cb, const int* __restrict__ idxArr,
        int* __restrict__ cursor, int* __restrict__ sorted,
        float* __restrict__ out) {
    int tid = threadIdx.x;
    int r = tid >> 2, seg = tid & 3;
    int gRow = blockIdx.x * 128 + r;
    int code = idxArr[gRow];
    if (seg == 0) {
        int pos = atomicAdd(&cursor[code], 1);
        sorted[pos] = gRow;
    }
    const float4* cbv = (const float4*)(cb + (long)code * D + seg * 64);
    float4* qv = (float4*)(out + Q_OFF + (long)gRow * D + seg * 64);
#pragma unroll 4
    for (int i = 0; i < 16; ++i) qv[i] = cbv[i];
}

// one wave per code: gather-sum its rows, write new_embedding_avg AND
// new_codebook (finalize folded in).
__global__ __launch_bounds__(256) void gather_sum_kernel(
        const float* __restrict__ z, const float* __restrict__ emb,
        const int* __restrict__ sorted, const int* __restrict__ cursor,
        const int* __restrict__ counts, const float* __restrict__ nacc,
        float* __restrict__ out) {
    int k = blockIdx.x * 4 + (threadIdx.x >> 6);
    int lane = threadIdx.x & 63;
    int cnt = counts[k];
    int start = cursor[k] - cnt;        // cursor was advanced by scatter
    float4 s = {0.f, 0.f, 0.f, 0.f};
    for (int i = 0; i < cnt; ++i) {
        int row = sorted[start + i];
        float4 v = *(const float4*)(z + (long)row * D + lane * 4);
        s.x += v.x; s.y += v.y; s.z += v.z; s.w += v.w;
    }
    float4 e = *(const float4*)(emb + (long)k * D + lane * 4);
    float4 o;
    o.x = e.x * DECAY + OMD * s.x;
    o.y = e.y * DECAY + OMD * s.y;
    o.z = e.z * DECAY + OMD * s.z;
    o.w = e.w * DECAY + OMD * s.w;
    *(float4*)(out + EMB_OFF + (long)k * D + lane * 4) = o;
    float n = *nacc;
    float ncs = out[CS_OFF + k];
    float smoothed = (ncs + EPS) / (n + (float)K * EPS) * n;
    float4 q;
    q.x = o.x / smoothed; q.y = o.y / smoothed;
    q.z = o.z / smoothed; q.w = o.w / smoothed;
    *(float4*)(out + CB_OFF + (long)k * D + lane * 4) = q;
}

extern "C" void kernel_launch(void* const* d_in, const int* in_sizes, int n_in,
                              void* d_out, int out_size, void* d_ws, size_t ws_size,
                              hipStream_t stream) {
    const float* z   = (const float*)d_in[0];
    const float* cb  = (const float*)d_in[1];
    const float* emb = (const float*)d_in[2];
    const float* cs  = (const float*)d_in[3];
    float* out = (float*)d_out;
    char* ws = (char*)d_ws;

    ulonglong2* tops = (ulonglong2*)(ws + WS_TOPS);
    unsigned long long* resolved = (unsigned long long*)(ws + WS_RES);
    int* idxArr = (int*)(ws + WS_IDX);
    float* c2 = (float*)(ws + WS_C2);
    int* flagRows = (int*)(ws + WS_FLAG);
    unsigned* flagCount = (unsigned*)(ws + WS_CNT);
    float* nacc = (float*)(ws + WS_CNT) + 1;
    int* counts = (int*)(ws + WS_CNTS);
    int* cursor = (int*)(ws + WS_CUR);
    int* sorted = (int*)(ws + WS_SORT);
    _Float16* cb16 = (_Float16*)(out + Q_OFF);   // scratch in quantized region

    prep_kernel<<<K, 64, 0, stream>>>(cb, cb16, c2, ws);
    dim3 ggrid(N / BMt, KSPLIT);
    gemm_kernel<<<ggrid, GT, 0, stream>>>(z, cb16, c2, tops);
    merge_kernel<<<N / 256, 256, 0, stream>>>(tops, out, idxArr, flagCount,
                                              flagRows, counts);
    dim3 rgrid(RSL, RKS);
    resolve_kernel<<<rgrid, 512, 0, stream>>>(z, cb, c2, flagCount, flagRows, resolved);
    writeback_kernel<<<N / 256, 256, 0, stream>>>(flagCount, flagRows, resolved,
                                                  idxArr, out, counts);
    scan_kernel<<<1, 1024, 0, stream>>>(counts, cs, cursor, out, nacc);
    scatter_quantize_kernel<<<N / 128, 512, 0, stream>>>(cb, idxArr, cursor,
                                                         sorted, out);
    gather_sum_kernel<<<K / 4, 256, 0, stream>>>(z, emb, sorted, cursor, counts,
                                                 nacc, out);
}

// Round 16
// 384.194 us; speedup vs baseline: 1.7473x; 1.4291x over previous
//
#include <hip/hip_runtime.h>

// EMA codebook update (VQ-VAE), MI355X. fp16-MFMA distance filter + exact
// fp32 rescore for near-ties. N=32768, K=8192, D=256.
// R16: gather_sum rebuilt — one block (8 waves) per code, rows strided
//      across waves (hub clusters parallelized 8x), indices preloaded
//      lane-parallel + shfl-broadcast (no dependent chain), 4-row ILP,
//      LDS combine. Gemm + rest identical to R15.

#define DECAY 0.99f
#define OMD 0.01f
#define EPS 1e-5f
#define DELTA 0.3f

constexpr int N = 32768, K = 8192, D = 256;
constexpr int KSPLIT = 2;               // gemm grid: 256 row-tiles x 2 code-splits
constexpr int BMt = 128, BNt = 128;     // gemm tile
constexpr int GT = 256;                 // gemm threads (4 waves: 2M x 2N, 64x64)

// resolve config
constexpr int RBM = 64;                 // flagged rows per group
constexpr int RBN = 128;                // codes per K-split
constexpr int RKS = 64;                 // K splits
constexpr int RSL = 16;                 // group slots

typedef _Float16 f16x8 __attribute__((ext_vector_type(8)));
typedef float f32x4 __attribute__((ext_vector_type(4)));

// d_out layout (floats, reference return order)
constexpr long Q_OFF   = 0;
constexpr long IDX_OFF = (long)N * D;
constexpr long CB_OFF  = IDX_OFF + N;
constexpr long EMB_OFF = CB_OFF + (long)K * D;
constexpr long CS_OFF  = EMB_OFF + (long)K * D;

// ws layout (bytes)
constexpr long WS_TOPS = 0;                          // ulonglong2[N*KSPLIT]
constexpr long WS_RES  = WS_TOPS + (long)N * 2 * 16; // u64[N] resolved
constexpr long WS_IDX  = WS_RES + (long)N * 8;       // int[N]
constexpr long WS_C2   = WS_IDX + (long)N * 4;       // float[K]
constexpr long WS_FLAG = WS_C2 + (long)K * 4;        // int[N] flagged rows
constexpr long WS_CNT  = WS_FLAG + (long)N * 4;      // [0] u32 count, [1] f32 nacc
constexpr long WS_CNTS = WS_CNT + 8;                 // int[K] histogram
constexpr long WS_CUR  = WS_CNTS + (long)K * 4;      // int[K] scan/cursor
constexpr long WS_SORT = WS_CUR + (long)K * 4;       // int[N] rows sorted by code

#define GLOAD_LDS16(g, l) __builtin_amdgcn_global_load_lds(                    \
    (const __attribute__((address_space(1))) void*)(g),                        \
    (__attribute__((address_space(3))) void*)(l), 16, 0, 0)

__device__ inline unsigned transScore(float s) {
    unsigned u = __float_as_uint(s);
    return u ^ ((unsigned)((int)u >> 31) | 0x80000000u);   // order-preserving
}
__device__ inline float untransScore(unsigned u) {
    return (u & 0x80000000u) ? __uint_as_float(u ^ 0x80000000u)
                             : __uint_as_float(~u);
}

// prep: c2 + fp32->fp16 codebook + all workspace init. grid K x 64.
__global__ void prep_kernel(const float* __restrict__ cb, _Float16* __restrict__ cb16,
                            float* __restrict__ c2, char* __restrict__ ws) {
    int k = blockIdx.x, lane = threadIdx.x;
    float4 v = ((const float4*)(cb + (long)k * D))[lane];
    float s = v.x * v.x + v.y * v.y + v.z * v.z + v.w * v.w;
    for (int off = 32; off; off >>= 1) s += __shfl_xor(s, off);
    if (lane == 0) c2[k] = s;
    union { _Float16 h[4]; unsigned long long u; } t;
    t.h[0] = (_Float16)v.x; t.h[1] = (_Float16)v.y;
    t.h[2] = (_Float16)v.z; t.h[3] = (_Float16)v.w;
    *(unsigned long long*)(cb16 + (long)k * D + lane * 4) = t.u;
    if (k < N / 64) ((unsigned long long*)(ws + WS_RES))[k * 64 + lane] = ~0ull;
    if (lane == 0) ((int*)(ws + WS_CNTS))[k] = 0;
    if (k == 0 && lane == 0) ((unsigned*)(ws + WS_CNT))[0] = 0u;
}

// B-staging slot q -> (code, 8-elem group) inverse of the LDS read swizzle
__device__ inline void bslot(int q, int& bc, int& bt) {
    int h = q >> 3, rr = q & 7;
    bc = 2 * h; bt = rr ^ (bc & 7);
    if (bt & 4) { bc++; bt = (rr ^ (bc & 7)) & 3; }
}

// ---------------- fp16 MFMA distance GEMM with top-2 tracking ----------------
__global__ __launch_bounds__(GT, 2) void gemm_kernel(
        const float* __restrict__ z, const _Float16* __restrict__ cb16,
        const float* __restrict__ c2, ulonglong2* __restrict__ tops) {
    __shared__ _Float16 As[BMt * 256];          // 64 KB, swizzled (r&15)
    __shared__ _Float16 Bs[2][BNt * 32];        // 2 x 8 KB, swizzled
    // total 81920 B exactly -> 2 blocks/CU. Top2 merge arrays union into Bs.

    const int tid = threadIdx.x;
    const int lane = tid & 63;
    const int wave = tid >> 6;                  // 4 waves: 2(M) x 2(N)
    const int wm = wave >> 1, wn = wave & 1;
    const long rowBase = (long)blockIdx.x * BMt;
    const int kbase = blockIdx.y * (K / KSPLIT);

    // ---- stage A (z rows) once: fp32 -> fp16, swizzled ----
    for (int i = 0; i < 16; ++i) {
        int id = tid + i * GT;                  // 4096 chunks of 8 floats
        int r = id >> 5, dseg = (id & 31) * 8;
        const float4* src = (const float4*)(z + (rowBase + r) * D + dseg);
        float4 v0 = src[0], v1 = src[1];
        union { _Float16 h[8]; ulonglong2 u; } t;
        t.h[0] = (_Float16)v0.x; t.h[1] = (_Float16)v0.y;
        t.h[2] = (_Float16)v0.z; t.h[3] = (_Float16)v0.w;
        t.h[4] = (_Float16)v1.x; t.h[5] = (_Float16)v1.y;
        t.h[6] = (_Float16)v1.z; t.h[7] = (_Float16)v1.w;
        int byte = (r * 256 + dseg) * 2;
        byte ^= (r & 15) << 4;                  // widened swizzle (both sides)
        *(ulonglong2*)((char*)As + byte) = t.u;
    }

    // ---- per-thread B-staging slots (2 per thread) ----
    int bc0, bt0, bc1, bt1;
    bslot(tid, bc0, bt0);
    bslot(tid + 256, bc1, bt1);
    char* ldsB0a = (char*)&Bs[0][0] + tid * 16;
    char* ldsB0b = (char*)&Bs[0][0] + (tid + 256) * 16;
    char* ldsB1a = (char*)&Bs[1][0] + tid * 16;
    char* ldsB1b = (char*)&Bs[1][0] + (tid + 256) * 16;

    // B chunk 0 (kb=0, dcI=0)
    GLOAD_LDS16(cb16 + ((long)(kbase + bc0) << 8) + bt0 * 8, ldsB0a);
    GLOAD_LDS16(cb16 + ((long)(kbase + bc1) << 8) + bt1 * 8, ldsB0b);
    __syncthreads();                            // drains vmcnt + LDS writes

    // per-thread A/B frag byte offsets. A: xor applied AFTER adding dc.
    int aBase[4], aSwz[4], bOff[4];
#pragma unroll
    for (int fr = 0; fr < 4; ++fr) {
        int r = wm * 64 + fr * 16 + (lane & 15);
        aBase[fr] = r * 512 + (lane >> 4) * 16;
        aSwz[fr] = (r & 15) << 4;
    }
#pragma unroll
    for (int fc = 0; fc < 4; ++fc) {
        int c = wn * 64 + fc * 16 + (lane & 15);
        int byte = c * 64 + (lane >> 4) * 16;
        bOff[fc] = byte ^ ((c & 7) << 4);
    }

    f32x4 acc[4][4];
    float bV[16], bT2[16];
    int bI[16];
#pragma unroll
    for (int s = 0; s < 16; ++s) { bV[s] = 3.4e38f; bT2[s] = 3.4e38f; bI[s] = 0; }
    float c2v[4];

    const int NCH = (K / KSPLIT / BNt) * 8;      // 256 chunks
    int cur = 0;
    for (int j = 0; j < NCH; ++j) {
        const int kb = j >> 3, dcI = j & 7, dc = dcI * 32;
        // stage next chunk direct-to-LDS
        if (j + 1 < NCH) {
            int jj = j + 1;
            long cbase2 = (long)(kbase + (jj >> 3) * BNt);
            int doff = (jj & 7) * 32;
            GLOAD_LDS16(cb16 + ((cbase2 + bc0) << 8) + doff + bt0 * 8,
                        cur ? ldsB0a : ldsB1a);
            GLOAD_LDS16(cb16 + ((cbase2 + bc1) << 8) + doff + bt1 * 8,
                        cur ? ldsB0b : ldsB1b);
        }
        if (dcI == 0) {
#pragma unroll
            for (int a = 0; a < 4; ++a)
#pragma unroll
                for (int b = 0; b < 4; ++b) acc[a][b] = (f32x4)0.f;
#pragma unroll
            for (int fc = 0; fc < 4; ++fc)
                c2v[fc] = c2[kbase + kb * BNt + wn * 64 + fc * 16 + (lane & 15)];
        }
        f16x8 aF[4], bF[4];
#pragma unroll
        for (int fr = 0; fr < 4; ++fr)
            aF[fr] = *(const f16x8*)((const char*)As +
                        ((aBase[fr] + dc * 2) ^ aSwz[fr]));
#pragma unroll
        for (int fc = 0; fc < 4; ++fc)
            bF[fc] = *(const f16x8*)((const char*)&Bs[cur][0] + bOff[fc]);
#pragma unroll
        for (int fr = 0; fr < 4; ++fr)
#pragma unroll
            for (int fc = 0; fc < 4; ++fc)
                acc[fr][fc] = __builtin_amdgcn_mfma_f32_16x16x32_f16(
                    aF[fr], bF[fc], acc[fr][fc], 0, 0, 0);
        if (dcI == 7) {
            // score + float top-2 (ties covered by DELTA rescore)
#pragma unroll
            for (int fc = 0; fc < 4; ++fc) {
                int gcol = kbase + kb * BNt + wn * 64 + fc * 16 + (lane & 15);
#pragma unroll
                for (int fr = 0; fr < 4; ++fr)
#pragma unroll
                    for (int r = 0; r < 4; ++r) {
                        float s = fmaf(-2.f, acc[fr][fc][r], c2v[fc]);
                        int slot = fr * 4 + r;
                        float t1o = bV[slot];
                        bT2[slot] = fminf(bT2[slot], fmaxf(s, t1o));
                        bool lt = s < t1o;
                        bV[slot] = lt ? s : t1o;
                        bI[slot] = lt ? gcol : bI[slot];
                    }
            }
        }
        __syncthreads();             // drain stage loads; guard Bs reuse
        cur ^= 1;
    }

    // intra-wave top2 merge over the 16 lanes sharing each row (float domain)
#pragma unroll
    for (int m = 1; m < 16; m <<= 1) {
#pragma unroll
        for (int s = 0; s < 16; ++s) {
            float ov = __shfl_xor(bV[s], m);
            int   oi = __shfl_xor(bI[s], m);
            float o2 = __shfl_xor(bT2[s], m);
            float nt2 = fminf(fminf(bT2[s], o2), fmaxf(bV[s], ov));
            bool take = ov < bV[s];
            bV[s] = take ? ov : bV[s];
            bI[s] = take ? oi : bI[s];
            bT2[s] = nt2;
        }
    }
    // cross-wave (2 wn waves) top2 merge via LDS atomicMin-displacement,
    // arrays unioned into Bs (K-loop done, last barrier passed).
    unsigned long long* L1 = (unsigned long long*)&Bs[0][0];   // 1 KB
    unsigned* L2s = (unsigned*)(L1 + BMt);                     // 512 B
    if (tid < BMt) { L1[tid] = ~0ull; L2s[tid] = 0xFFFFFFFFu; }
    __syncthreads();
    if ((lane & 15) == 0) {
#pragma unroll
        for (int s = 0; s < 16; ++s) {
            int row = wm * 64 + (s >> 2) * 16 + (lane >> 4) * 4 + (s & 3);
            unsigned long long t1 =
                ((unsigned long long)transScore(bV[s]) << 32) | (unsigned)bI[s];
            unsigned long long old1 = atomicMin(&L1[row], t1);
            unsigned long long cand = t1 < old1 ? old1 : t1;
            atomicMin(&L2s[row], (unsigned)(cand >> 32));
            atomicMin(&L2s[row], transScore(bT2[s]));
        }
    }
    __syncthreads();
    if (tid < BMt) {
        ulonglong2 v; v.x = L1[tid]; v.y = (unsigned long long)L2s[tid];
        tops[(rowBase + tid) * KSPLIT + blockIdx.y] = v;
    }
}

// merge + histogram of confidently-resolved rows
__global__ void merge_kernel(const ulonglong2* __restrict__ tops,
                             float* __restrict__ out, int* __restrict__ idxArr,
                             unsigned* __restrict__ flagCount,
                             int* __restrict__ flagRows, int* __restrict__ counts) {
    int row = blockIdx.x * 256 + threadIdx.x;
    ulonglong2 a = tops[row * 2], b = tops[row * 2 + 1];
    unsigned long long t1 = a.x < b.x ? a.x : b.x;
    unsigned a1 = (unsigned)(a.x >> 32), b1 = (unsigned)(b.x >> 32);
    unsigned mx = a1 > b1 ? a1 : b1;
    unsigned t2 = (unsigned)a.y < (unsigned)b.y ? (unsigned)a.y : (unsigned)b.y;
    t2 = t2 < mx ? t2 : mx;
    float s1 = untransScore((unsigned)(t1 >> 32));
    float s2 = untransScore(t2);
    int idx = (int)(t1 & 0xFFFFFFFFull);
    idxArr[row] = idx;
    out[IDX_OFF + row] = (float)idx;
    if (s2 - s1 <= DELTA) {
        unsigned p = atomicAdd(flagCount, 1u);
        flagRows[p] = row;
    } else {
        atomicAdd(&counts[idx], 1);
    }
}

// exact fp32 rescore of flagged rows. Grid (RSL slots, RKS splits of RBN codes).
__global__ __launch_bounds__(512) void resolve_kernel(
        const float* __restrict__ z, const float* __restrict__ cb,
        const float* __restrict__ c2, const unsigned* __restrict__ flagCount,
        const int* __restrict__ flagRows, unsigned long long* __restrict__ resolved) {
    __shared__ float zT[32][RBM + 4];       // [d][row], 8.7 KB
    __shared__ float cT[32][RBN + 4];       // [d][code], 16.9 KB
    __shared__ float c2s[RBN];
    __shared__ int rid[RBM];

    const int cnt = (int)*flagCount;
    const int tid = threadIdx.x;
    const int tx = tid & 31, ty = tid >> 5;     // ty 0..15
    const int rbase = ty * 4, cbase = tx * 4;
    const int k0 = blockIdx.y * RBN;

    if (tid < RBN) c2s[tid] = c2[k0 + tid];

    for (int g = blockIdx.x; g * RBM < cnt; g += RSL) {
        __syncthreads();                    // previous group fully done
        if (tid < RBM) {
            int fi = g * RBM + tid;
            rid[tid] = flagRows[fi < cnt ? fi : cnt - 1];   // pad = dup (harmless)
        }

        float acc[4][4];
#pragma unroll
        for (int r = 0; r < 4; ++r)
#pragma unroll
            for (int c = 0; c < 4; ++c) acc[r][c] = 0.f;

        for (int dc = 0; dc < D; dc += 32) {
            __syncthreads();                // rid visible; prev reads done
            // stage z: 64 rows x 8 float4 = 512 slots (1 per thread)
            {
                int row = tid >> 3, dq = tid & 7;
                float4 v = *(const float4*)(z + (long)rid[row] * D + dc + dq * 4);
                zT[dq * 4 + 0][row] = v.x; zT[dq * 4 + 1][row] = v.y;
                zT[dq * 4 + 2][row] = v.z; zT[dq * 4 + 3][row] = v.w;
            }
            // stage cT: 128 codes x 8 float4 = 1024 slots (2 per thread)
#pragma unroll
            for (int i = 0; i < 2; ++i) {
                int id = tid + i * 512;
                int c = id >> 3, dq = id & 7;
                float4 w = *(const float4*)(cb + (long)(k0 + c) * D + dc + dq * 4);
                cT[dq * 4 + 0][c] = w.x; cT[dq * 4 + 1][c] = w.y;
                cT[dq * 4 + 2][c] = w.z; cT[dq * 4 + 3][c] = w.w;
            }
            __syncthreads();
#pragma unroll
            for (int d = 0; d < 32; ++d) {
                float a[4], b[4];
                *(float4*)&a[0] = *(const float4*)&zT[d][rbase];   // bcast x2
                *(float4*)&b[0] = *(const float4*)&cT[d][cbase];
#pragma unroll
                for (int r = 0; r < 4; ++r)
#pragma unroll
                    for (int c = 0; c < 4; ++c)
                        acc[r][c] = fmaf(a[r], b[c], acc[r][c]);
            }
        }
        // score + per-row best over this block's 128 codes
        float bestV[4]; int bestI[4];
#pragma unroll
        for (int r = 0; r < 4; ++r) { bestV[r] = 3.4e38f; bestI[r] = 0; }
#pragma unroll
        for (int c = 0; c < 4; ++c) {
            float cc = c2s[cbase + c];
            int col = k0 + cbase + c;
#pragma unroll
            for (int r = 0; r < 4; ++r) {
                float score = fmaf(-2.f, acc[r][c], cc);
                if (score < bestV[r]) { bestV[r] = score; bestI[r] = col; }
            }
        }
        // reduce over the 32 tx lanes (codes); first-index ties
#pragma unroll
        for (int off = 16; off; off >>= 1) {
#pragma unroll
            for (int r = 0; r < 4; ++r) {
                float ov = __shfl_xor(bestV[r], off);
                int   oi = __shfl_xor(bestI[r], off);
                if (ov < bestV[r] || (ov == bestV[r] && oi < bestI[r])) {
                    bestV[r] = ov; bestI[r] = oi;
                }
            }
        }
        if (tx == 0) {
#pragma unroll
            for (int r = 0; r < 4; ++r) {
                unsigned long long u =
                    ((unsigned long long)transScore(bestV[r]) << 32)
                    | (unsigned)bestI[r];
                atomicMin(&resolved[rid[rbase + r]], u);
            }
        }
    }
}

// writeback + histogram of flagged rows
__global__ void writeback_kernel(const unsigned* __restrict__ flagCount,
                                 const int* __restrict__ flagRows,
                                 const unsigned long long* __restrict__ resolved,
                                 int* __restrict__ idxArr, float* __restrict__ out,
                                 int* __restrict__ counts) {
    int i = blockIdx.x * 256 + threadIdx.x;
    if (i < (int)*flagCount) {
        int row = flagRows[i];
        int idx = (int)(resolved[row] & 0xFFFFFFFFull);
        idxArr[row] = idx;
        out[IDX_OFF + row] = (float)idx;
        atomicAdd(&counts[idx], 1);
    }
}

// single block: exclusive scan of counts -> cursor, CS output, n scalar
__global__ __launch_bounds__(1024) void scan_kernel(
        const int* __restrict__ counts, const float* __restrict__ cs,
        int* __restrict__ cursor, float* __restrict__ out,
        float* __restrict__ nacc) {
    __shared__ int wtot[16];
    __shared__ float csred[16];
    int tid = threadIdx.x;
    int lane = tid & 63, w = tid >> 6;
    int base = tid * 8;                 // 8192 / 1024
    int4 c0 = ((const int4*)(counts + base))[0];
    int4 c1 = ((const int4*)(counts + base))[1];
    float4 f0 = ((const float4*)(cs + base))[0];
    float4 f1 = ((const float4*)(cs + base))[1];
    int local[8] = {c0.x, c0.y, c0.z, c0.w, c1.x, c1.y, c1.z, c1.w};
    float csv[8] = {f0.x, f0.y, f0.z, f0.w, f1.x, f1.y, f1.z, f1.w};
    int sum = 0; float csum = 0.f;
#pragma unroll
    for (int i = 0; i < 8; ++i) { sum += local[i]; csum += csv[i]; }
    // wave-inclusive scan of per-thread sums
    int inc = sum;
#pragma unroll
    for (int off = 1; off < 64; off <<= 1) {
        int v = __shfl_up(inc, off);
        if (lane >= off) inc += v;
    }
    // cs partial reduce per wave
    for (int off = 32; off; off >>= 1) csum += __shfl_xor(csum, off);
    if (lane == 63) wtot[w] = inc;
    if (lane == 0) csred[w] = csum;
    __syncthreads();
    // wave 0 scans the 16 wave totals (exclusive)
    if (w == 0 && lane < 16) {
        int v = wtot[lane];
        int s2 = v;
#pragma unroll
        for (int off = 1; off < 16; off <<= 1) {
            int t = __shfl_up(s2, off);
            if (lane >= off) s2 += t;
        }
        wtot[lane] = s2 - v;            // exclusive wave offset
    }
    __syncthreads();
    int run = wtot[w] + (inc - sum);    // exclusive prefix of this thread chunk
#pragma unroll
    for (int i = 0; i < 8; ++i) {
        cursor[base + i] = run;
        out[CS_OFF + base + i] = csv[i] * DECAY + OMD * (float)local[i];
        run += local[i];
    }
    if (tid == 0) {
        float t = 0.f;
#pragma unroll
        for (int i = 0; i < 16; ++i) t += csred[i];
        *nacc = t * DECAY + OMD * (float)N;   // sum(counts) == N exactly
    }
}

// scatter (counting-sort placement) fused with quantized-gather copy
__global__ __launch_bounds__(512) void scatter_quantize_kernel(
        const float* __restrict__ cb, const int* __restrict__ idxArr,
        int* __restrict__ cursor, int* __restrict__ sorted,
        float* __restrict__ out) {
    int tid = threadIdx.x;
    int r = tid >> 2, seg = tid & 3;
    int gRow = blockIdx.x * 128 + r;
    int code = idxArr[gRow];
    if (seg == 0) {
        int pos = atomicAdd(&cursor[code], 1);
        sorted[pos] = gRow;
    }
    const float4* cbv = (const float4*)(cb + (long)code * D + seg * 64);
    float4* qv = (float4*)(out + Q_OFF + (long)gRow * D + seg * 64);
#pragma unroll 4
    for (int i = 0; i < 16; ++i) qv[i] = cbv[i];
}

// one BLOCK (8 waves) per code: waves stride rows by 8 (hub parallelism),
// indices preloaded lane-parallel + shfl broadcast (no dependent chain),
// 4-row ILP, LDS combine; writes new_embedding_avg AND new_codebook.
__global__ __launch_bounds__(512) void gather_sum_kernel(
        const float* __restrict__ z, const float* __restrict__ emb,
        const int* __restrict__ sorted, const int* __restrict__ cursor,
        const int* __restrict__ counts, const float* __restrict__ nacc,
        float* __restrict__ out) {
    __shared__ float4 part[8][64];
    const int k = blockIdx.x;
    const int w = threadIdx.x >> 6, lane = threadIdx.x & 63;
    const int cnt = counts[k];
    const int start = cursor[k] - cnt;      // cursor was advanced by scatter

    float4 s = {0.f, 0.f, 0.f, 0.f};
    // wave w sums rows i = w, w+8, w+16, ... ; 64 indices preloaded per tile
    for (int j0 = 0; j0 * 8 + w < cnt; j0 += 64) {
        int ii = w + 8 * (j0 + lane);
        int idx = (ii < cnt) ? sorted[start + ii] : 0;
        int m = (cnt - w - 8 * j0 + 7) >> 3;    // valid j's in this tile
        if (m > 64) m = 64;
        for (int t = 0; t < m; t += 4) {
            int r0 = __shfl(idx, t);
            int r1 = __shfl(idx, t + 1);
            int r2 = __shfl(idx, t + 2);
            int r3 = __shfl(idx, t + 3);
            float4 a0 = *(const float4*)(z + (long)r0 * D + lane * 4);
            s.x += a0.x; s.y += a0.y; s.z += a0.z; s.w += a0.w;
            if (t + 1 < m) {
                float4 a1 = *(const float4*)(z + (long)r1 * D + lane * 4);
                s.x += a1.x; s.y += a1.y; s.z += a1.z; s.w += a1.w;
            }
            if (t + 2 < m) {
                float4 a2 = *(const float4*)(z + (long)r2 * D + lane * 4);
                s.x += a2.x; s.y += a2.y; s.z += a2.z; s.w += a2.w;
            }
            if (t + 3 < m) {
                float4 a3 = *(const float4*)(z + (long)r3 * D + lane * 4);
                s.x += a3.x; s.y += a3.y; s.z += a3.z; s.w += a3.w;
            }
        }
    }
    part[w][lane] = s;
    __syncthreads();
    if (w == 0) {
#pragma unroll
        for (int q = 1; q < 8; ++q) {
            float4 p = part[q][lane];
            s.x += p.x; s.y += p.y; s.z += p.z; s.w += p.w;
        }
        float4 e = *(const float4*)(emb + (long)k * D + lane * 4);
        float4 o;
        o.x = e.x * DECAY + OMD * s.x;
        o.y = e.y * DECAY + OMD * s.y;
        o.z = e.z * DECAY + OMD * s.z;
        o.w = e.w * DECAY + OMD * s.w;
        *(float4*)(out + EMB_OFF + (long)k * D + lane * 4) = o;
        float n = *nacc;
        float ncs = out[CS_OFF + k];
        float smoothed = (ncs + EPS) / (n + (float)K * EPS) * n;
        float4 q4;
        q4.x = o.x / smoothed; q4.y = o.y / smoothed;
        q4.z = o.z / smoothed; q4.w = o.w / smoothed;
        *(float4*)(out + CB_OFF + (long)k * D + lane * 4) = q4;
    }
}

extern "C" void kernel_launch(void* const* d_in, const int* in_sizes, int n_in,
                              void* d_out, int out_size, void* d_ws, size_t ws_size,
                              hipStream_t stream) {
    const float* z   = (const float*)d_in[0];
    const float* cb  = (const float*)d_in[1];
    const float* emb = (const float*)d_in[2];
    const float* cs  = (const float*)d_in[3];
    float* out = (float*)d_out;
    char* ws = (char*)d_ws;

    ulonglong2* tops = (ulonglong2*)(ws + WS_TOPS);
    unsigned long long* resolved = (unsigned long long*)(ws + WS_RES);
    int* idxArr = (int*)(ws + WS_IDX);
    float* c2 = (float*)(ws + WS_C2);
    int* flagRows = (int*)(ws + WS_FLAG);
    unsigned* flagCount = (unsigned*)(ws + WS_CNT);
    float* nacc = (float*)(ws + WS_CNT) + 1;
    int* counts = (int*)(ws + WS_CNTS);
    int* cursor = (int*)(ws + WS_CUR);
    int* sorted = (int*)(ws + WS_SORT);
    _Float16* cb16 = (_Float16*)(out + Q_OFF);   // scratch in quantized region

    prep_kernel<<<K, 64, 0, stream>>>(cb, cb16, c2, ws);
    dim3 ggrid(N / BMt, KSPLIT);
    gemm_kernel<<<ggrid, GT, 0, stream>>>(z, cb16, c2, tops);
    merge_kernel<<<N / 256, 256, 0, stream>>>(tops, out, idxArr, flagCount,
                                              flagRows, counts);
    dim3 rgrid(RSL, RKS);
    resolve_kernel<<<rgrid, 512, 0, stream>>>(z, cb, c2, flagCount, flagRows, resolved);
    writeback_kernel<<<N / 256, 256, 0, stream>>>(flagCount, flagRows, resolved,
                                                  idxArr, out, counts);
    scan_kernel<<<1, 1024, 0, stream>>>(counts, cs, cursor, out, nacc);
    scatter_quantize_kernel<<<N / 128, 512, 0, stream>>>(cb, idxArr, cursor,
                                                         sorted, out);
    gather_sum_kernel<<<K, 512, 0, stream>>>(z, emb, sorted, cursor, counts,
                                             nacc, out);
}